// Round 5
// baseline (1602.230 us; speedup 1.0000x reference)
//
#include <hip/hip_runtime.h>
#include <hip/hip_bf16.h>

using bf16 = __hip_bfloat16;
typedef unsigned short ushort_t;

// Interface model (settled rounds 0-4):
//   INPUTS: fp32 (detector-proven: raw fp32 NaN-pattern hits; r2==r3==r4).
//   OUTPUT: fp32 (reference returns jnp.float32; r2/r3/r4's bf16 writes read
//   back as packed fp32 words reproduced the exact 0.650390625 signature).
// Kernel set: r3 fast pipeline, proven bit-equivalent (at bf16 granularity)
// to the r4 dumb reference pipeline.

static constexpr int B  = 8;
static constexpr int C  = 512;
static constexpr int N  = 1024;   // H*W
static constexpr int NH = 8;
static constexpr int DH = 64;
static constexpr int CQ = 128;    // C/4

// ws layout (bytes), 27.3 MB:
//   qkv bf16 [3][B,NH,N,DH] : 0        .. 25165824   (o overwrites q third)
//   h1  bf16 [B,CQ,N]       : 25165824 .. 27262976
//   att fp32 [B,N]          : 27262976 .. 27295744
//   flag int                : 27295744 .. 27295748
static constexpr size_t QKV_OFF  = 0;
static constexpr size_t H1_OFF   = 25165824;
static constexpr size_t ATT_OFF  = 27262976;
static constexpr size_t FLAG_OFF = 27295744;

__device__ __forceinline__ float ldin(const void* p, size_t i, bool f32) {
  return f32 ? ((const float*)p)[i]
             : __bfloat162float(((const bf16*)p)[i]);
}

// ---------------------------------------------------------------------------
// K0: dtype detect. flag=1 -> inputs fp32, flag=0 -> bf16.
// ---------------------------------------------------------------------------
__global__ __launch_bounds__(256) void k_detect(const ushort_t* __restrict__ u,
                                                int* __restrict__ flag) {
  __shared__ int any;
  if (threadIdx.x == 0) any = 0;
  __syncthreads();
  int hit = 0;
  for (int i = threadIdx.x; i < 16384; i += 256) {
    ushort_t v = u[i];
    hit |= ((v & 0x7F80u) == 0x7F80u) ? 1 : 0;   // bf16 inf/NaN exponent
  }
  if (hit) atomicOr(&any, 1);
  __syncthreads();
  if (threadIdx.x == 0) flag[0] = any;
}

// ---------------------------------------------------------------------------
// K1: qkv[b,o,p] = sum_c W_qkv[o,c] * x[b,c,p]; scatter into q/k/v [B,NH,N,DH]
// o = s*512 + h*64 + d; p = n
// ---------------------------------------------------------------------------
__global__ __launch_bounds__(256) void k_qkv(const void* __restrict__ W,
                                             const void* __restrict__ x,
                                             bf16* __restrict__ qkv,
                                             const int* __restrict__ flag) {
  const bool f32 = flag[0] != 0;
  __shared__ float Ws[64][33];
  __shared__ float Xs[32][65];
  const int pt = blockIdx.x, ot = blockIdx.y, b = blockIdx.z;
  const int p0 = pt * 64, o0 = ot * 64;
  const int t = threadIdx.x, tx = t & 15, ty = t >> 4;
  float acc[4][4] = {};
  for (int kc = 0; kc < C; kc += 32) {
    __syncthreads();
#pragma unroll
    for (int i = 0; i < 8; ++i) {
      int e = t + 256 * i;
      Ws[e >> 5][e & 31] = ldin(W, (size_t)(o0 + (e >> 5)) * C + kc + (e & 31), f32);
    }
#pragma unroll
    for (int i = 0; i < 8; ++i) {
      int e = t + 256 * i;
      Xs[e >> 6][e & 63] =
          ldin(x, (size_t)b * C * N + (size_t)(kc + (e >> 6)) * N + p0 + (e & 63), f32);
    }
    __syncthreads();
#pragma unroll
    for (int kk = 0; kk < 32; ++kk) {
      float a[4], bb[4];
#pragma unroll
      for (int i = 0; i < 4; ++i) a[i] = Ws[i * 16 + tx][kk];
#pragma unroll
      for (int j = 0; j < 4; ++j) bb[j] = Xs[kk][j * 16 + ty];
#pragma unroll
      for (int i = 0; i < 4; ++i)
#pragma unroll
        for (int j = 0; j < 4; ++j) acc[i][j] += a[i] * bb[j];
    }
  }
  const int s = o0 >> 9;          // 0:q 1:k 2:v  (block-constant)
  const int h = (o0 >> 6) & 7;    // head (block-constant)
  bf16* dst = qkv + (size_t)s * (B * NH * N * DH) + (size_t)(b * NH + h) * N * DH;
#pragma unroll
  for (int i = 0; i < 4; ++i) {
    const int d = i * 16 + tx;
#pragma unroll
    for (int j = 0; j < 4; ++j) {
      const int p = p0 + j * 16 + ty;
      dst[(size_t)p * DH + d] = __float2bfloat16(acc[i][j]);
    }
  }
}

// ---------------------------------------------------------------------------
// K2: flash attention per (b,h); O overwrites this block's own q rows.
// ---------------------------------------------------------------------------
__global__ __launch_bounds__(256) void k_attn(bf16* __restrict__ qkv) {
  __shared__ float Ks[64][68];
  __shared__ float Vs[64][68];
  __shared__ float Ss[64][65];
  __shared__ float row_m[64], row_l[64], row_a[64];
  const int qt = blockIdx.x, bh = blockIdx.y;
  const int t = threadIdx.x, qr = t & 63, grp = t >> 6;
  const bf16* kp = qkv + (size_t)B * NH * N * DH;
  const bf16* vp = kp + (size_t)B * NH * N * DH;

  {
    const bf16* qb = qkv + ((size_t)bh * N + qt * 64) * DH;
#pragma unroll
    for (int i = 0; i < 16; ++i) {
      int e = t + 256 * i;
      Ss[e >> 6][e & 63] = __bfloat162float(qb[e]);
    }
  }
  __syncthreads();
  float qreg[64];
#pragma unroll
  for (int d = 0; d < 64; ++d) qreg[d] = Ss[qr][d];
  if (t < 64) { row_m[t] = -1e30f; row_l[t] = 0.f; }
  float o_acc[16] = {};

  for (int mt = 0; mt < 16; ++mt) {
    __syncthreads();
    {
      const bf16* kb = kp + ((size_t)bh * N + mt * 64) * DH;
      const bf16* vb = vp + ((size_t)bh * N + mt * 64) * DH;
#pragma unroll
      for (int i = 0; i < 16; ++i) {
        int e = t + 256 * i;
        Ks[e >> 6][e & 63] = __bfloat162float(kb[e]);
        Vs[e >> 6][e & 63] = __bfloat162float(vb[e]);
      }
    }
    __syncthreads();
#pragma unroll
    for (int jj = 0; jj < 16; ++jj) {
      const int j = grp * 16 + jj;
      const float4* krow = (const float4*)&Ks[j][0];
      float s = 0.f;
#pragma unroll
      for (int d4 = 0; d4 < 16; ++d4) {
        float4 kv = krow[d4];
        s += qreg[4 * d4 + 0] * kv.x + qreg[4 * d4 + 1] * kv.y +
             qreg[4 * d4 + 2] * kv.z + qreg[4 * d4 + 3] * kv.w;
      }
      Ss[qr][j] = s * 0.125f;
    }
    __syncthreads();
    if (t < 64) {
      float m_old = row_m[t];
      float mn = m_old;
      for (int j = 0; j < 64; ++j) mn = fmaxf(mn, Ss[t][j]);
      float alpha = __expf(m_old - mn);
      float l = row_l[t] * alpha;
      for (int j = 0; j < 64; ++j) {
        float pj = __expf(Ss[t][j] - mn);
        Ss[t][j] = pj;
        l += pj;
      }
      row_m[t] = mn; row_l[t] = l; row_a[t] = alpha;
    }
    __syncthreads();
    const float alpha = row_a[qr];
#pragma unroll
    for (int i = 0; i < 16; ++i) o_acc[i] *= alpha;
    for (int j = 0; j < 64; ++j) {
      const float pj = Ss[qr][j];
      const float4* vrow = (const float4*)&Vs[j][grp * 16];
      float4 v0 = vrow[0], v1 = vrow[1], v2 = vrow[2], v3 = vrow[3];
      o_acc[0]  += pj * v0.x;  o_acc[1]  += pj * v0.y;
      o_acc[2]  += pj * v0.z;  o_acc[3]  += pj * v0.w;
      o_acc[4]  += pj * v1.x;  o_acc[5]  += pj * v1.y;
      o_acc[6]  += pj * v1.z;  o_acc[7]  += pj * v1.w;
      o_acc[8]  += pj * v2.x;  o_acc[9]  += pj * v2.y;
      o_acc[10] += pj * v2.z;  o_acc[11] += pj * v2.w;
      o_acc[12] += pj * v3.x;  o_acc[13] += pj * v3.y;
      o_acc[14] += pj * v3.z;  o_acc[15] += pj * v3.w;
    }
  }
  const float inv = 1.f / row_l[qr];
  bf16* ob = qkv + ((size_t)bh * N + qt * 64 + qr) * DH + grp * 16;
#pragma unroll
  for (int i = 0; i < 16; ++i) ob[i] = __float2bfloat16(o_acc[i] * inv);
}

// ---------------------------------------------------------------------------
// K3: out[b,co,p] = b_proj[co] + sum_ci Wp[co,ci] * o_rs[b,ci,p]
// o_rs[b,ci,p] = o[b, h=(p&511)>>6, n=2*ci+(p>>9), d=p&63]
// out stored FP32 directly into d_out (output 0).
// ---------------------------------------------------------------------------
__global__ __launch_bounds__(256) void k_proj(const void* __restrict__ Wp,
                                              const void* __restrict__ bp,
                                              const bf16* __restrict__ obuf,
                                              float* __restrict__ outd,
                                              const int* __restrict__ flag) {
  const bool f32 = flag[0] != 0;
  __shared__ float Ws[64][33];
  __shared__ float Os[32][65];
  const int pt = blockIdx.x, ct = blockIdx.y, b = blockIdx.z;
  const int p0 = pt * 64, co0 = ct * 64;
  const int h   = (p0 & 511) >> 6;
  const int eps = p0 >> 9;
  const int t = threadIdx.x, tx = t & 15, ty = t >> 4;
  float acc[4][4] = {};
  const bf16* ob = obuf + ((size_t)(b * NH + h) * N + eps) * DH;
  for (int kc = 0; kc < C; kc += 32) {
    __syncthreads();
#pragma unroll
    for (int i = 0; i < 8; ++i) {
      int e = t + 256 * i;
      Ws[e >> 5][e & 31] = ldin(Wp, (size_t)(co0 + (e >> 5)) * C + kc + (e & 31), f32);
    }
#pragma unroll
    for (int i = 0; i < 8; ++i) {
      int e = t + 256 * i;
      Os[e >> 6][e & 63] = __bfloat162float(ob[(size_t)(kc + (e >> 6)) * (2 * DH) + (e & 63)]);
    }
    __syncthreads();
#pragma unroll
    for (int kk = 0; kk < 32; ++kk) {
      float a[4], bb[4];
#pragma unroll
      for (int i = 0; i < 4; ++i) a[i] = Ws[i * 16 + tx][kk];
#pragma unroll
      for (int j = 0; j < 4; ++j) bb[j] = Os[kk][j * 16 + ty];
#pragma unroll
      for (int i = 0; i < 4; ++i)
#pragma unroll
        for (int j = 0; j < 4; ++j) acc[i][j] += a[i] * bb[j];
    }
  }
#pragma unroll
  for (int i = 0; i < 4; ++i) {
    const int co = co0 + i * 16 + tx;
    const float bias = ldin(bp, co, f32);
#pragma unroll
    for (int j = 0; j < 4; ++j) {
      const int p = p0 + j * 16 + ty;
      outd[(size_t)b * C * N + (size_t)co * N + p] = acc[i][j] + bias;
    }
  }
}

// ---------------------------------------------------------------------------
// K4: h1[b,j,p] = relu(b_att1[j] + sum_ci W_att1[j,ci] * out[b,ci,p]); bf16 h1
// ---------------------------------------------------------------------------
__global__ __launch_bounds__(256) void k_att1(const void* __restrict__ W1,
                                              const void* __restrict__ b1,
                                              const float* __restrict__ outd,
                                              bf16* __restrict__ h1b,
                                              const int* __restrict__ flag) {
  const bool f32 = flag[0] != 0;
  __shared__ float Ws[64][33];
  __shared__ float Is[32][65];
  const int pt = blockIdx.x, jt = blockIdx.y, b = blockIdx.z;
  const int p0 = pt * 64, j0 = jt * 64;
  const int t = threadIdx.x, tx = t & 15, ty = t >> 4;
  float acc[4][4] = {};
  const float* ib = outd + (size_t)b * C * N + p0;
  for (int kc = 0; kc < C; kc += 32) {
    __syncthreads();
#pragma unroll
    for (int i = 0; i < 8; ++i) {
      int e = t + 256 * i;
      Ws[e >> 5][e & 31] = ldin(W1, (size_t)(j0 + (e >> 5)) * C + kc + (e & 31), f32);
    }
#pragma unroll
    for (int i = 0; i < 8; ++i) {
      int e = t + 256 * i;
      Is[e >> 6][e & 63] = ib[(size_t)(kc + (e >> 6)) * N + (e & 63)];
    }
    __syncthreads();
#pragma unroll
    for (int kk = 0; kk < 32; ++kk) {
      float a[4], bb[4];
#pragma unroll
      for (int i = 0; i < 4; ++i) a[i] = Ws[i * 16 + tx][kk];
#pragma unroll
      for (int j = 0; j < 4; ++j) bb[j] = Is[kk][j * 16 + ty];
#pragma unroll
      for (int i = 0; i < 4; ++i)
#pragma unroll
        for (int j = 0; j < 4; ++j) acc[i][j] += a[i] * bb[j];
    }
  }
#pragma unroll
  for (int i = 0; i < 4; ++i) {
    const int jo = j0 + i * 16 + tx;
    const float bias = ldin(b1, jo, f32);
#pragma unroll
    for (int j = 0; j < 4; ++j) {
      const int p = p0 + j * 16 + ty;
      h1b[(size_t)b * CQ * N + (size_t)jo * N + p] =
          __float2bfloat16(fmaxf(acc[i][j] + bias, 0.f));
    }
  }
}

// ---------------------------------------------------------------------------
// K5: att[b,p] = sigmoid(b_att2 + sum_j W_att2[j] * h1[b,j,p]);
//     fp32 ws copy + FP32 output-1.
// ---------------------------------------------------------------------------
__global__ __launch_bounds__(256) void k_att2(const void* __restrict__ W2,
                                              const void* __restrict__ b2,
                                              const bf16* __restrict__ h1b,
                                              float* __restrict__ attb,
                                              float* __restrict__ out1,
                                              const int* __restrict__ flag) {
  const bool f32 = flag[0] != 0;
  const int idx = blockIdx.x * 256 + threadIdx.x;   // 0..8191
  const int b = idx >> 10, p = idx & 1023;
  float acc = ldin(b2, 0, f32);
  const bf16* hb = h1b + (size_t)b * CQ * N + p;
  for (int j = 0; j < CQ; ++j)
    acc += ldin(W2, j, f32) * __bfloat162float(hb[(size_t)j * N]);
  const float sg = 1.f / (1.f + __expf(-acc));
  attb[idx] = sg;
  out1[idx] = sg;
}

// ---------------------------------------------------------------------------
// K6: out0[b,c,p] *= att[b,p]  (in-place gate of fp32 d_out)
// ---------------------------------------------------------------------------
__global__ __launch_bounds__(256) void k_mul(float* __restrict__ out0,
                                             const float* __restrict__ attb) {
  const int idx = blockIdx.x * 256 + threadIdx.x;   // 0..4194303
  const int b = idx >> 19;
  const int p = idx & 1023;
  out0[idx] = out0[idx] * attb[b * 1024 + p];
}

// ---------------------------------------------------------------------------
extern "C" void kernel_launch(void* const* d_in, const int* in_sizes, int n_in,
                              void* d_out, int out_size, void* d_ws, size_t ws_size,
                              hipStream_t stream) {
  const void* x     = d_in[0];
  const void* Wqkv  = d_in[1];
  const void* Wproj = d_in[2];
  const void* bproj = d_in[3];
  const void* Watt1 = d_in[4];
  const void* batt1 = d_in[5];
  const void* Watt2 = d_in[6];
  const void* batt2 = d_in[7];

  char* ws = (char*)d_ws;
  bf16*  qkvb = (bf16*)(ws + QKV_OFF);
  bf16*  h1b  = (bf16*)(ws + H1_OFF);
  float* attb = (float*)(ws + ATT_OFF);
  int*   flag = (int*)(ws + FLAG_OFF);

  float* out0 = (float*)d_out;
  float* out1 = out0 + (size_t)B * C * N;   // 4194304 floats

  k_detect<<<1, 256, 0, stream>>>((const ushort_t*)x, flag);
  k_qkv <<<dim3(16, 24, 8), 256, 0, stream>>>(Wqkv, x, qkvb, flag);
  k_attn<<<dim3(16, 64),    256, 0, stream>>>(qkvb);
  k_proj<<<dim3(16, 8, 8),  256, 0, stream>>>(Wproj, bproj, qkvb, out0, flag);
  k_att1<<<dim3(16, 2, 8),  256, 0, stream>>>(Watt1, batt1, out0, h1b, flag);
  k_att2<<<32,    256, 0, stream>>>(Watt2, batt2, h1b, attb, out1, flag);
  k_mul <<<16384, 256, 0, stream>>>(out0, attb);
}

// Round 6
// 382.428 us; speedup vs baseline: 4.1896x; 4.1896x over previous
//
#include <hip/hip_runtime.h>
#include <hip/hip_bf16.h>

using bf16 = __hip_bfloat16;
typedef __bf16 bf16x8 __attribute__((ext_vector_type(8)));
typedef float  f32x4  __attribute__((ext_vector_type(4)));

// Interface model (settled r0-r5): inputs fp32, output fp32. r5 PASSED.
// This round: MFMA bf16 16x16x32 for k_qkv + k_attn (the 1410/1602 us).
// Layouts (guide, m89/m91/m118/m120 verified):
//   A-frag: lane holds A[m=lane&15][k=(lane>>4)*8+j] -> row-major [m][k] tile
//   B-frag: lane holds B[k=(lane>>4)*8+j][n=lane&15] -> store tile as [n][k]
//   C/D:    row=(lane>>4)*4+reg, col=lane&15
// bf16 LDS tiles use XOR-swizzled 16B atoms (atom' = atom ^ (row&7)):
// bank-balanced for both the staging writes and the b128 frag reads.

static constexpr int B  = 8;
static constexpr int C  = 512;
static constexpr int N  = 1024;   // H*W
static constexpr int NH = 8;
static constexpr int DH = 64;
static constexpr int CQ = 128;    // C/4

// ws layout (bytes), 27.3 MB:
//   qkv bf16 [3][B,NH,N,DH] : 0        .. 25165824   (o overwrites q third)
//   h1  bf16 [B,CQ,N]       : 25165824 .. 27262976
//   att fp32 [B,N]          : 27262976 .. 27295744
static constexpr size_t QKV_OFF  = 0;
static constexpr size_t H1_OFF   = 25165824;
static constexpr size_t ATT_OFF  = 27262976;

__device__ __forceinline__ unsigned short f2bfu(float f) {
  union { float f; unsigned u; } v; v.f = f;
  unsigned u = v.u;
  return (unsigned short)((u + 0x7fffu + ((u >> 16) & 1u)) >> 16);  // RNE
}
__device__ __forceinline__ unsigned pack2(float lo, float hi) {
  return (unsigned)f2bfu(lo) | ((unsigned)f2bfu(hi) << 16);
}
// swizzled element index in a 64x64 bf16 tile (16B atoms XORed by row&7)
__device__ __forceinline__ int swz(int row, int col) {
  return row * 64 + ((((col >> 3) ^ row) & 7) << 3) + (col & 7);
}
// load an A/B fragment (8 bf16, 16B) from a swizzled tile
__device__ __forceinline__ bf16x8 ldfrag(const short* tl, int row, int kk, int lane) {
  const int atom = 4 * kk + (lane >> 4);
  return *(const bf16x8*)&tl[row * 64 + (((atom ^ row) & 7) << 3)];
}

// ---------------------------------------------------------------------------
// K1 (MFMA): qkv[b,o,p] = sum_c W[o,c] x[b,c,p], scatter q/k/v [B,NH,N,DH].
// D[m=p][n=o]: A = x^T tile [p][c], B = W tile [o][c] (stored [n][k]).
// ---------------------------------------------------------------------------
__global__ __launch_bounds__(256) void k_qkv(const float* __restrict__ W,
                                             const float* __restrict__ x,
                                             bf16* __restrict__ qkv) {
  __shared__ __align__(16) short Wl[64 * 64];
  __shared__ __align__(16) short Xt[64 * 64];
  const int pt = blockIdx.x, ot = blockIdx.y, b = blockIdx.z;
  const int p0 = pt * 64, o0 = ot * 64;
  const int t = threadIdx.x, l = t & 63, w = t >> 6;
  f32x4 acc[4] = {};
  for (int kc = 0; kc < C; kc += 64) {
    __syncthreads();
    {  // stage W[o0..+64][kc..+64] -> Wl (bf16, swizzled)
      const int o = t & 63, g = t >> 6;
      const float4* wr = (const float4*)&W[(size_t)(o0 + o) * C + kc + g * 16];
#pragma unroll
      for (int u = 0; u < 4; ++u) {
        float4 f = wr[u];
        int c0 = g * 16 + 4 * u;
        *(unsigned*)&Wl[swz(o, c0)]     = pack2(f.x, f.y);
        *(unsigned*)&Wl[swz(o, c0 + 2)] = pack2(f.z, f.w);
      }
    }
    {  // stage x^T: Xt[p][c] (pack c-pairs)
      const int cp = t & 31, g = t >> 5;          // g 0..7 -> p chunk
      const int c0 = kc + 2 * cp;
      const float* xr0 = &x[((size_t)b * C + c0) * N + p0 + g * 8];
      const float* xr1 = xr0 + N;
      float a0[8], a1[8];
      *(float4*)&a0[0] = ((const float4*)xr0)[0];
      *(float4*)&a0[4] = ((const float4*)xr0)[1];
      *(float4*)&a1[0] = ((const float4*)xr1)[0];
      *(float4*)&a1[4] = ((const float4*)xr1)[1];
#pragma unroll
      for (int i = 0; i < 8; ++i)
        *(unsigned*)&Xt[swz(g * 8 + i, 2 * cp)] = pack2(a0[i], a1[i]);
    }
    __syncthreads();
    const int mrow = w * 16 + (l & 15);
#pragma unroll
    for (int kk = 0; kk < 2; ++kk) {
      bf16x8 a = ldfrag(Xt, mrow, kk, l);
#pragma unroll
      for (int nt = 0; nt < 4; ++nt) {
        bf16x8 bf = ldfrag(Wl, nt * 16 + (l & 15), kk, l);
        acc[nt] = __builtin_amdgcn_mfma_f32_16x16x32_bf16(a, bf, acc[nt], 0, 0, 0);
      }
    }
  }
  const int s = o0 >> 9, h = (o0 >> 6) & 7;  // block-constant
  bf16* dst = qkv + (size_t)s * (B * NH * N * DH) + (size_t)(b * NH + h) * N * DH;
  const int p_base = p0 + w * 16 + 4 * (l >> 4);
#pragma unroll
  for (int nt = 0; nt < 4; ++nt) {
    const int d = nt * 16 + (l & 15);
#pragma unroll
    for (int r = 0; r < 4; ++r)
      dst[(size_t)(p_base + r) * DH + d] = __float2bfloat16(acc[nt][r]);
  }
}

// ---------------------------------------------------------------------------
// K2 (MFMA flash attention): per (b,h), Q-tile 64 rows, K/V tiles of 64.
// Online softmax in registers (shfl_xor over 16-lane groups).
// P goes C-layout -> LDS (fp32, stride 68) -> A-layout for PV.
// O overwrites this block's own q rows.
// ---------------------------------------------------------------------------
__global__ __launch_bounds__(256) void k_attn(bf16* __restrict__ qkv) {
  __shared__ __align__(16) short Ql[64 * 64];
  __shared__ __align__(16) short Kl[64 * 64];
  __shared__ __align__(16) short Vt[64 * 64];   // V^T: [dim][key]
  __shared__ __align__(16) float Pl[64 * 68];   // per-wave 16x64, stride 68
  const int qt = blockIdx.x, bh = blockIdx.y;
  const int t = threadIdx.x, l = t & 63, w = t >> 6;
  const bf16* kp = qkv + (size_t)B * NH * N * DH;
  const bf16* vp = kp + (size_t)B * NH * N * DH;

  {  // stage Q (contiguous 8KB, swizzled)
    const uint4* gq = (const uint4*)(qkv + ((size_t)bh * N + qt * 64) * DH);
    for (int c = t; c < 512; c += 256) {
      int row = c >> 3, atom = c & 7;
      *(uint4*)&Ql[row * 64 + (((atom ^ row) & 7) << 3)] = gq[c];
    }
  }
  __syncthreads();
  const int mrow = w * 16 + (l & 15);
  bf16x8 qf[2] = { ldfrag(Ql, mrow, 0, l), ldfrag(Ql, mrow, 1, l) };
  float m_run[4] = {-1e30f, -1e30f, -1e30f, -1e30f};
  float l_run[4] = {};
  f32x4 oacc[4] = {};
  float* Plw = &Pl[w * 16 * 68];

  for (int mt = 0; mt < 16; ++mt) {
    __syncthreads();   // prior tile's K/V reads complete
    {  // stage K (direct) + V^T (pack key-pairs)
      const uint4* gk = (const uint4*)(kp + ((size_t)bh * N + mt * 64) * DH);
      for (int c = t; c < 512; c += 256) {
        int row = c >> 3, atom = c & 7;
        *(uint4*)&Kl[row * 64 + (((atom ^ row) & 7) << 3)] = gk[c];
      }
      const uint4* gv = (const uint4*)(vp + ((size_t)bh * N + mt * 64) * DH);
      const int kpr = t & 31, g = t >> 5;
      union { uint4 v; unsigned short s[8]; } v0, v1;
      v0.v = gv[16 * kpr + g];
      v1.v = gv[16 * kpr + 8 + g];
#pragma unroll
      for (int j = 0; j < 8; ++j)
        *(unsigned*)&Vt[swz(g * 8 + j, 2 * kpr)] =
            (unsigned)v0.s[j] | ((unsigned)v1.s[j] << 16);
    }
    __syncthreads();
    // S = Q K^T / 8
    f32x4 sacc[4] = {};
#pragma unroll
    for (int kk = 0; kk < 2; ++kk)
#pragma unroll
      for (int nt = 0; nt < 4; ++nt) {
        bf16x8 bf = ldfrag(Kl, nt * 16 + (l & 15), kk, l);
        sacc[nt] = __builtin_amdgcn_mfma_f32_16x16x32_bf16(qf[kk], bf, sacc[nt], 0, 0, 0);
      }
#pragma unroll
    for (int nt = 0; nt < 4; ++nt) sacc[nt] *= 0.125f;
    // online softmax per row (reg r of this lane's quad-group)
    float alpha[4];
#pragma unroll
    for (int r = 0; r < 4; ++r) {
      float mloc = fmaxf(fmaxf(sacc[0][r], sacc[1][r]),
                         fmaxf(sacc[2][r], sacc[3][r]));
#pragma unroll
      for (int off = 1; off < 16; off <<= 1)
        mloc = fmaxf(mloc, __shfl_xor(mloc, off));
      const float mn = fmaxf(m_run[r], mloc);
      alpha[r] = __expf(m_run[r] - mn);
      m_run[r] = mn;
      float lloc = 0.f;
      const int prow = 4 * (l >> 4) + r;
#pragma unroll
      for (int nt = 0; nt < 4; ++nt) {
        float pv = __expf(sacc[nt][r] - mn);
        Plw[prow * 68 + (l & 15) + 16 * nt] = pv;
        lloc += pv;
      }
#pragma unroll
      for (int off = 1; off < 16; off <<= 1)
        lloc += __shfl_xor(lloc, off);
      l_run[r] = l_run[r] * alpha[r] + lloc;
    }
#pragma unroll
    for (int nt = 0; nt < 4; ++nt)
#pragma unroll
      for (int r = 0; r < 4; ++r)
        oacc[nt][r] *= alpha[r];
    // O += P V   (P from LDS in A-layout; V^T rows give B-frags)
#pragma unroll
    for (int kk = 0; kk < 2; ++kk) {
      const float* pr = &Plw[(l & 15) * 68 + kk * 32 + 8 * (l >> 4)];
      bf16x8 pa;
#pragma unroll
      for (int j = 0; j < 8; ++j) pa[j] = (__bf16)pr[j];
#pragma unroll
      for (int nt = 0; nt < 4; ++nt) {
        bf16x8 bf = ldfrag(Vt, nt * 16 + (l & 15), kk, l);
        oacc[nt] = __builtin_amdgcn_mfma_f32_16x16x32_bf16(pa, bf, oacc[nt], 0, 0, 0);
      }
    }
  }
  const int qrow = qt * 64 + w * 16 + 4 * (l >> 4);
#pragma unroll
  for (int r = 0; r < 4; ++r) {
    const float inv = 1.f / l_run[r];
#pragma unroll
    for (int nt = 0; nt < 4; ++nt)
      qkv[((size_t)bh * N + qrow + r) * DH + nt * 16 + (l & 15)] =
          __float2bfloat16(oacc[nt][r] * inv);
  }
}

// ---------------------------------------------------------------------------
// K3: out[b,co,p] = b_proj[co] + sum_ci Wp[co,ci] * o_rs[b,ci,p]  (fp32 tiled)
// o_rs[b,ci,p] = o[b, h=(p&511)>>6, n=2*ci+(p>>9), d=p&63]
// ---------------------------------------------------------------------------
__global__ __launch_bounds__(256) void k_proj(const float* __restrict__ Wp,
                                              const float* __restrict__ bp,
                                              const bf16* __restrict__ obuf,
                                              float* __restrict__ outd) {
  __shared__ float Ws[64][33];
  __shared__ float Os[32][65];
  const int pt = blockIdx.x, ct = blockIdx.y, b = blockIdx.z;
  const int p0 = pt * 64, co0 = ct * 64;
  const int h   = (p0 & 511) >> 6;
  const int eps = p0 >> 9;
  const int t = threadIdx.x, tx = t & 15, ty = t >> 4;
  float acc[4][4] = {};
  const bf16* ob = obuf + ((size_t)(b * NH + h) * N + eps) * DH;
  for (int kc = 0; kc < C; kc += 32) {
    __syncthreads();
#pragma unroll
    for (int i = 0; i < 8; ++i) {
      int e = t + 256 * i;
      Ws[e >> 5][e & 31] = Wp[(size_t)(co0 + (e >> 5)) * C + kc + (e & 31)];
    }
#pragma unroll
    for (int i = 0; i < 8; ++i) {
      int e = t + 256 * i;
      Os[e >> 6][e & 63] = __bfloat162float(ob[(size_t)(kc + (e >> 6)) * (2 * DH) + (e & 63)]);
    }
    __syncthreads();
#pragma unroll
    for (int kk = 0; kk < 32; ++kk) {
      float a[4], bb[4];
#pragma unroll
      for (int i = 0; i < 4; ++i) a[i] = Ws[i * 16 + tx][kk];
#pragma unroll
      for (int j = 0; j < 4; ++j) bb[j] = Os[kk][j * 16 + ty];
#pragma unroll
      for (int i = 0; i < 4; ++i)
#pragma unroll
        for (int j = 0; j < 4; ++j) acc[i][j] += a[i] * bb[j];
    }
  }
#pragma unroll
  for (int i = 0; i < 4; ++i) {
    const int co = co0 + i * 16 + tx;
    const float bias = bp[co];
#pragma unroll
    for (int j = 0; j < 4; ++j) {
      const int p = p0 + j * 16 + ty;
      outd[(size_t)b * C * N + (size_t)co * N + p] = acc[i][j] + bias;
    }
  }
}

// ---------------------------------------------------------------------------
// K4: h1[b,j,p] = relu(b_att1[j] + sum_ci W_att1[j,ci] * out[b,ci,p]); bf16 h1
// ---------------------------------------------------------------------------
__global__ __launch_bounds__(256) void k_att1(const float* __restrict__ W1,
                                              const float* __restrict__ b1,
                                              const float* __restrict__ outd,
                                              bf16* __restrict__ h1b) {
  __shared__ float Ws[64][33];
  __shared__ float Is[32][65];
  const int pt = blockIdx.x, jt = blockIdx.y, b = blockIdx.z;
  const int p0 = pt * 64, j0 = jt * 64;
  const int t = threadIdx.x, tx = t & 15, ty = t >> 4;
  float acc[4][4] = {};
  const float* ib = outd + (size_t)b * C * N + p0;
  for (int kc = 0; kc < C; kc += 32) {
    __syncthreads();
#pragma unroll
    for (int i = 0; i < 8; ++i) {
      int e = t + 256 * i;
      Ws[e >> 5][e & 31] = W1[(size_t)(j0 + (e >> 5)) * C + kc + (e & 31)];
    }
#pragma unroll
    for (int i = 0; i < 8; ++i) {
      int e = t + 256 * i;
      Is[e >> 6][e & 63] = ib[(size_t)(kc + (e >> 6)) * N + (e & 63)];
    }
    __syncthreads();
#pragma unroll
    for (int kk = 0; kk < 32; ++kk) {
      float a[4], bb[4];
#pragma unroll
      for (int i = 0; i < 4; ++i) a[i] = Ws[i * 16 + tx][kk];
#pragma unroll
      for (int j = 0; j < 4; ++j) bb[j] = Is[kk][j * 16 + ty];
#pragma unroll
      for (int i = 0; i < 4; ++i)
#pragma unroll
        for (int j = 0; j < 4; ++j) acc[i][j] += a[i] * bb[j];
    }
  }
#pragma unroll
  for (int i = 0; i < 4; ++i) {
    const int jo = j0 + i * 16 + tx;
    const float bias = b1[jo];
#pragma unroll
    for (int j = 0; j < 4; ++j) {
      const int p = p0 + j * 16 + ty;
      h1b[(size_t)b * CQ * N + (size_t)jo * N + p] =
          __float2bfloat16(fmaxf(acc[i][j] + bias, 0.f));
    }
  }
}

// ---------------------------------------------------------------------------
// K5: att[b,p] = sigmoid(b_att2 + sum_j W_att2[j] * h1[b,j,p])
// ---------------------------------------------------------------------------
__global__ __launch_bounds__(256) void k_att2(const float* __restrict__ W2,
                                              const float* __restrict__ b2,
                                              const bf16* __restrict__ h1b,
                                              float* __restrict__ attb,
                                              float* __restrict__ out1) {
  const int idx = blockIdx.x * 256 + threadIdx.x;   // 0..8191
  const int b = idx >> 10, p = idx & 1023;
  float acc = b2[0];
  const bf16* hb = h1b + (size_t)b * CQ * N + p;
  for (int j = 0; j < CQ; ++j)
    acc += W2[j] * __bfloat162float(hb[(size_t)j * N]);
  const float sg = 1.f / (1.f + __expf(-acc));
  attb[idx] = sg;
  out1[idx] = sg;
}

// ---------------------------------------------------------------------------
// K6: out0 *= att  (in-place gate of fp32 d_out)
// ---------------------------------------------------------------------------
__global__ __launch_bounds__(256) void k_mul(float* __restrict__ out0,
                                             const float* __restrict__ attb) {
  const int idx = blockIdx.x * 256 + threadIdx.x;   // 0..4194303
  const int b = idx >> 19;
  const int p = idx & 1023;
  out0[idx] = out0[idx] * attb[b * 1024 + p];
}

// ---------------------------------------------------------------------------
extern "C" void kernel_launch(void* const* d_in, const int* in_sizes, int n_in,
                              void* d_out, int out_size, void* d_ws, size_t ws_size,
                              hipStream_t stream) {
  const float* x     = (const float*)d_in[0];
  const float* Wqkv  = (const float*)d_in[1];
  const float* Wproj = (const float*)d_in[2];
  const float* bproj = (const float*)d_in[3];
  const float* Watt1 = (const float*)d_in[4];
  const float* batt1 = (const float*)d_in[5];
  const float* Watt2 = (const float*)d_in[6];
  const float* batt2 = (const float*)d_in[7];

  char* ws = (char*)d_ws;
  bf16*  qkvb = (bf16*)(ws + QKV_OFF);
  bf16*  h1b  = (bf16*)(ws + H1_OFF);
  float* attb = (float*)(ws + ATT_OFF);

  float* out0 = (float*)d_out;
  float* out1 = out0 + (size_t)B * C * N;   // 4194304 floats

  k_qkv <<<dim3(16, 24, 8), 256, 0, stream>>>(Wqkv, x, qkvb);
  k_attn<<<dim3(16, 64),    256, 0, stream>>>(qkvb);
  k_proj<<<dim3(16, 8, 8),  256, 0, stream>>>(Wproj, bproj, qkvb, out0);
  k_att1<<<dim3(16, 2, 8),  256, 0, stream>>>(Watt1, batt1, out0, h1b);
  k_att2<<<32,    256, 0, stream>>>(Watt2, batt2, h1b, attb, out1);
  k_mul <<<16384, 256, 0, stream>>>(out0, attb);
}

// Round 7
// 291.739 us; speedup vs baseline: 5.4920x; 1.3109x over previous
//
#include <hip/hip_runtime.h>
#include <hip/hip_bf16.h>

using bf16 = __hip_bfloat16;
typedef __bf16 bf16x8 __attribute__((ext_vector_type(8)));
typedef float  f32x4  __attribute__((ext_vector_type(4)));

// Interface model (settled r0-r5): inputs fp32, output fp32.
// r6: MFMA for qkv+attn -> 382 us. r7: MFMA for proj+att1, register
// prefetch of global staging in all tiled kernels (staging-latency was the
// bottleneck: MfmaUtil 4.7%, VALUBusy 18.5%, HBM 7% -> nothing saturated).
// MFMA 16x16x32 layouts (verified r6 PASS):
//   A-frag: lane holds A[m=lane&15][k=(lane>>4)*8+j] (row-major [m][k] tile)
//   B-frag: lane holds B[k][n=lane&15] (tile stored [n][k])
//   C/D:    row=(lane>>4)*4+reg, col=lane&15
// LDS tiles: XOR-swizzled 16B atoms (atom' = atom ^ (row&7)) -> 0 conflicts.

static constexpr int B  = 8;
static constexpr int C  = 512;
static constexpr int N  = 1024;   // H*W
static constexpr int NH = 8;
static constexpr int DH = 64;
static constexpr int CQ = 128;    // C/4

// ws layout (bytes), 27.3 MB:
static constexpr size_t QKV_OFF  = 0;          // qkv bf16 [3][B,NH,N,DH] (o overwrites q)
static constexpr size_t H1_OFF   = 25165824;   // h1 bf16 [B,CQ,N]
static constexpr size_t ATT_OFF  = 27262976;   // att fp32 [B,N]

__device__ __forceinline__ unsigned short f2bfu(float f) {
  union { float f; unsigned u; } v; v.f = f;
  unsigned u = v.u;
  return (unsigned short)((u + 0x7fffu + ((u >> 16) & 1u)) >> 16);  // RNE
}
__device__ __forceinline__ unsigned pack2(float lo, float hi) {
  return (unsigned)f2bfu(lo) | ((unsigned)f2bfu(hi) << 16);
}
__device__ __forceinline__ int swz(int row, int col) {
  return row * 64 + ((((col >> 3) ^ row) & 7) << 3) + (col & 7);
}
__device__ __forceinline__ bf16x8 ldfrag(const short* tl, int row, int kk, int lane) {
  const int atom = 4 * kk + (lane >> 4);
  return *(const bf16x8*)&tl[row * 64 + (((atom ^ row) & 7) << 3)];
}

// ---------------------------------------------------------------------------
// K1 (MFMA + prefetch): qkv[b,o,p] = sum_c W[o,c] x[b,c,p] -> q/k/v [B,NH,N,DH]
// D[m=p][n=o]: A = x^T tile [p][c] (pack-transposed), B = W tile [o][c].
// ---------------------------------------------------------------------------
__global__ __launch_bounds__(256) void k_qkv(const float* __restrict__ W,
                                             const float* __restrict__ x,
                                             bf16* __restrict__ qkv) {
  __shared__ __align__(16) short Wl[64 * 64];
  __shared__ __align__(16) short Xt[64 * 64];
  const int pt = blockIdx.x, ot = blockIdx.y, b = blockIdx.z;
  const int p0 = pt * 64, o0 = ot * 64;
  const int t = threadIdx.x, l = t & 63, w = t >> 6;
  const int so = t & 63, sg = t >> 6;   // W staging: row so, col-chunk sg*16
  const int cp = t & 31, g = t >> 5;    // X staging: c-pair cp, p-chunk g*8
  const float* wsrc = &W[(size_t)(o0 + so) * C + sg * 16];
  const float* xsrc = &x[((size_t)b * C + 2 * cp) * N + p0 + g * 8];
  float4 wreg[4], xreg[4];
  auto ld = [&](int kc) {
    const float4* wp_ = (const float4*)(wsrc + kc);
    wreg[0] = wp_[0]; wreg[1] = wp_[1]; wreg[2] = wp_[2]; wreg[3] = wp_[3];
    const float4* x0_ = (const float4*)(xsrc + (size_t)kc * N);
    xreg[0] = x0_[0]; xreg[1] = x0_[1];
    const float4* x1_ = (const float4*)(xsrc + (size_t)(kc + 1) * N);
    xreg[2] = x1_[0]; xreg[3] = x1_[1];
  };
  f32x4 acc[4] = {};
  ld(0);
  for (int kc = 0; kc < C; kc += 64) {
    __syncthreads();
#pragma unroll
    for (int u = 0; u < 4; ++u) {
      const int c0 = sg * 16 + 4 * u;
      *(unsigned*)&Wl[swz(so, c0)]     = pack2(wreg[u].x, wreg[u].y);
      *(unsigned*)&Wl[swz(so, c0 + 2)] = pack2(wreg[u].z, wreg[u].w);
    }
    {
      float a0[8], a1[8];
      *(float4*)&a0[0] = xreg[0]; *(float4*)&a0[4] = xreg[1];
      *(float4*)&a1[0] = xreg[2]; *(float4*)&a1[4] = xreg[3];
#pragma unroll
      for (int i = 0; i < 8; ++i)
        *(unsigned*)&Xt[swz(g * 8 + i, 2 * cp)] = pack2(a0[i], a1[i]);
    }
    __syncthreads();
    if (kc + 64 < C) ld(kc + 64);   // prefetch overlaps MFMA phase
    const int mrow = w * 16 + (l & 15);
#pragma unroll
    for (int kk = 0; kk < 2; ++kk) {
      bf16x8 a = ldfrag(Xt, mrow, kk, l);
#pragma unroll
      for (int nt = 0; nt < 4; ++nt) {
        bf16x8 bf = ldfrag(Wl, nt * 16 + (l & 15), kk, l);
        acc[nt] = __builtin_amdgcn_mfma_f32_16x16x32_bf16(a, bf, acc[nt], 0, 0, 0);
      }
    }
  }
  const int s = o0 >> 9, h = (o0 >> 6) & 7;
  bf16* dst = qkv + (size_t)s * (B * NH * N * DH) + (size_t)(b * NH + h) * N * DH;
  const int p_base = p0 + w * 16 + 4 * (l >> 4);
#pragma unroll
  for (int nt = 0; nt < 4; ++nt) {
    const int d = nt * 16 + (l & 15);
#pragma unroll
    for (int r = 0; r < 4; ++r)
      dst[(size_t)(p_base + r) * DH + d] = __float2bfloat16(acc[nt][r]);
  }
}

// ---------------------------------------------------------------------------
// K2 (MFMA flash attention + prefetch): per (b,h), Q-tile 64, K/V tiles 64.
// ---------------------------------------------------------------------------
__global__ __launch_bounds__(256) void k_attn(bf16* __restrict__ qkv) {
  __shared__ __align__(16) short Ql[64 * 64];
  __shared__ __align__(16) short Kl[64 * 64];
  __shared__ __align__(16) short Vt[64 * 64];   // V^T: [dim][key]
  __shared__ __align__(16) float Pl[64 * 68];
  const int qt = blockIdx.x, bh = blockIdx.y;
  const int t = threadIdx.x, l = t & 63, w = t >> 6;
  const bf16* kp = qkv + (size_t)B * NH * N * DH;
  const bf16* vp = kp + (size_t)B * NH * N * DH;
  const uint4* gkb = (const uint4*)(kp + (size_t)bh * N * DH);
  const uint4* gvb = (const uint4*)(vp + (size_t)bh * N * DH);
  const int kpr = t & 31, g = t >> 5;

  {  // stage Q
    const uint4* gq = (const uint4*)(qkv + ((size_t)bh * N + qt * 64) * DH);
    for (int c = t; c < 512; c += 256) {
      int row = c >> 3, atom = c & 7;
      *(uint4*)&Ql[row * 64 + (((atom ^ row) & 7) << 3)] = gq[c];
    }
  }
  __syncthreads();
  const int mrow = w * 16 + (l & 15);
  bf16x8 qf[2] = { ldfrag(Ql, mrow, 0, l), ldfrag(Ql, mrow, 1, l) };
  float m_run[4] = {-1e30f, -1e30f, -1e30f, -1e30f};
  float l_run[4] = {};
  f32x4 oacc[4] = {};
  float* Plw = &Pl[w * 16 * 68];

  union u4s { uint4 v; unsigned short s[8]; };
  uint4 kreg0, kreg1; u4s v0, v1;
  auto ld = [&](int mt) {
    const uint4* gk = gkb + mt * 512;
    kreg0 = gk[t]; kreg1 = gk[t + 256];
    const uint4* gv = gvb + mt * 512;
    v0.v = gv[16 * kpr + g]; v1.v = gv[16 * kpr + 8 + g];
  };
  ld(0);

  for (int mt = 0; mt < 16; ++mt) {
    __syncthreads();   // prior tile's LDS reads complete
    {  // write prefetched K (direct) + V^T (pack key-pairs)
      const int r0 = t >> 3, a0 = t & 7;
      *(uint4*)&Kl[r0 * 64 + (((a0 ^ r0) & 7) << 3)] = kreg0;
      const int r1 = r0 + 32;
      *(uint4*)&Kl[r1 * 64 + (((a0 ^ r1) & 7) << 3)] = kreg1;
#pragma unroll
      for (int j = 0; j < 8; ++j)
        *(unsigned*)&Vt[swz(g * 8 + j, 2 * kpr)] =
            (unsigned)v0.s[j] | ((unsigned)v1.s[j] << 16);
    }
    __syncthreads();
    if (mt < 15) ld(mt + 1);   // prefetch overlaps compute
    // S = Q K^T / 8
    f32x4 sacc[4] = {};
#pragma unroll
    for (int kk = 0; kk < 2; ++kk)
#pragma unroll
      for (int nt = 0; nt < 4; ++nt) {
        bf16x8 bf = ldfrag(Kl, nt * 16 + (l & 15), kk, l);
        sacc[nt] = __builtin_amdgcn_mfma_f32_16x16x32_bf16(qf[kk], bf, sacc[nt], 0, 0, 0);
      }
#pragma unroll
    for (int nt = 0; nt < 4; ++nt) sacc[nt] *= 0.125f;
    float alpha[4];
#pragma unroll
    for (int r = 0; r < 4; ++r) {
      float mloc = fmaxf(fmaxf(sacc[0][r], sacc[1][r]),
                         fmaxf(sacc[2][r], sacc[3][r]));
#pragma unroll
      for (int off = 1; off < 16; off <<= 1)
        mloc = fmaxf(mloc, __shfl_xor(mloc, off));
      const float mn = fmaxf(m_run[r], mloc);
      alpha[r] = __expf(m_run[r] - mn);
      m_run[r] = mn;
      float lloc = 0.f;
      const int prow = 4 * (l >> 4) + r;
#pragma unroll
      for (int nt = 0; nt < 4; ++nt) {
        float pv = __expf(sacc[nt][r] - mn);
        Plw[prow * 68 + (l & 15) + 16 * nt] = pv;
        lloc += pv;
      }
#pragma unroll
      for (int off = 1; off < 16; off <<= 1)
        lloc += __shfl_xor(lloc, off);
      l_run[r] = l_run[r] * alpha[r] + lloc;
    }
#pragma unroll
    for (int nt = 0; nt < 4; ++nt)
#pragma unroll
      for (int r = 0; r < 4; ++r)
        oacc[nt][r] *= alpha[r];
#pragma unroll
    for (int kk = 0; kk < 2; ++kk) {
      const float* pr = &Plw[(l & 15) * 68 + kk * 32 + 8 * (l >> 4)];
      bf16x8 pa;
#pragma unroll
      for (int j = 0; j < 8; ++j) pa[j] = (__bf16)pr[j];
#pragma unroll
      for (int nt = 0; nt < 4; ++nt) {
        bf16x8 bf = ldfrag(Vt, nt * 16 + (l & 15), kk, l);
        oacc[nt] = __builtin_amdgcn_mfma_f32_16x16x32_bf16(pa, bf, oacc[nt], 0, 0, 0);
      }
    }
  }
  const int qrow = qt * 64 + w * 16 + 4 * (l >> 4);
#pragma unroll
  for (int r = 0; r < 4; ++r) {
    const float inv = 1.f / l_run[r];
#pragma unroll
    for (int nt = 0; nt < 4; ++nt)
      qkv[((size_t)bh * N + qrow + r) * DH + nt * 16 + (l & 15)] =
          __float2bfloat16(oacc[nt][r] * inv);
  }
}

// ---------------------------------------------------------------------------
// K3 (MFMA + prefetch): out[b,co,p] = bias + sum_ci Wp[co,ci]*o_rs[b,ci,p]
// o_rs[ci][pp] = obase[(2ci+eps)*64 + pp]  (h,eps block-constant). fp32 out.
// D[m=pp][n=co]: A = o_rs^T [pp][ci] (pack), B = Wp [co][ci].
// ---------------------------------------------------------------------------
__global__ __launch_bounds__(256) void k_proj(const float* __restrict__ Wp,
                                              const float* __restrict__ bp,
                                              const bf16* __restrict__ obuf,
                                              float* __restrict__ outd) {
  __shared__ __align__(16) short Wl[64 * 64];
  __shared__ __align__(16) short Ot[64 * 64];
  const int pt = blockIdx.x, ct = blockIdx.y, b = blockIdx.z;
  const int p0 = pt * 64, co0 = ct * 64;
  const int h = (p0 & 511) >> 6, eps = p0 >> 9;
  const int t = threadIdx.x, l = t & 63, w = t >> 6;
  const int so = t & 63, sg = t >> 6;
  const int cp = t & 31, g = t >> 5;
  const float* wsrc = &Wp[(size_t)(co0 + so) * C + sg * 16];
  const bf16* obase = obuf + (size_t)(b * NH + h) * N * DH;
  union u4s { uint4 v; unsigned short s[8]; };
  float4 wreg[4]; u4s o0r, o1r;
  auto ld = [&](int kc) {
    const float4* wp_ = (const float4*)(wsrc + kc);
    wreg[0] = wp_[0]; wreg[1] = wp_[1]; wreg[2] = wp_[2]; wreg[3] = wp_[3];
    const int ci0 = kc + 2 * cp;
    o0r.v = *(const uint4*)(obase + (size_t)(2 * ci0 + eps) * 64 + g * 8);
    o1r.v = *(const uint4*)(obase + (size_t)(2 * ci0 + 2 + eps) * 64 + g * 8);
  };
  f32x4 acc[4] = {};
  ld(0);
  for (int kc = 0; kc < C; kc += 64) {
    __syncthreads();
#pragma unroll
    for (int u = 0; u < 4; ++u) {
      const int c0 = sg * 16 + 4 * u;
      *(unsigned*)&Wl[swz(so, c0)]     = pack2(wreg[u].x, wreg[u].y);
      *(unsigned*)&Wl[swz(so, c0 + 2)] = pack2(wreg[u].z, wreg[u].w);
    }
#pragma unroll
    for (int i = 0; i < 8; ++i)
      *(unsigned*)&Ot[swz(g * 8 + i, 2 * cp)] =
          (unsigned)o0r.s[i] | ((unsigned)o1r.s[i] << 16);
    __syncthreads();
    if (kc + 64 < C) ld(kc + 64);
    const int mrow = w * 16 + (l & 15);
#pragma unroll
    for (int kk = 0; kk < 2; ++kk) {
      bf16x8 a = ldfrag(Ot, mrow, kk, l);
#pragma unroll
      for (int nt = 0; nt < 4; ++nt) {
        bf16x8 bf = ldfrag(Wl, nt * 16 + (l & 15), kk, l);
        acc[nt] = __builtin_amdgcn_mfma_f32_16x16x32_bf16(a, bf, acc[nt], 0, 0, 0);
      }
    }
  }
  const int pbase = w * 16 + 4 * (l >> 4);
#pragma unroll
  for (int nt = 0; nt < 4; ++nt) {
    const int co = co0 + nt * 16 + (l & 15);
    const float bias = bp[co];
#pragma unroll
    for (int r = 0; r < 4; ++r)
      outd[(size_t)b * C * N + (size_t)co * N + p0 + pbase + r] = acc[nt][r] + bias;
  }
}

// ---------------------------------------------------------------------------
// K4 (MFMA + prefetch): h1[b,j,p] = relu(b1[j] + sum_ci W1[j,ci]*out[b,ci,p])
// Same structure as k_qkv (out fp32 rows are p-contiguous -> pack-transpose).
// ---------------------------------------------------------------------------
__global__ __launch_bounds__(256) void k_att1(const float* __restrict__ W1,
                                              const float* __restrict__ b1,
                                              const float* __restrict__ outd,
                                              bf16* __restrict__ h1b) {
  __shared__ __align__(16) short Wl[64 * 64];
  __shared__ __align__(16) short Xt[64 * 64];
  const int pt = blockIdx.x, jt = blockIdx.y, b = blockIdx.z;
  const int p0 = pt * 64, j0 = jt * 64;
  const int t = threadIdx.x, l = t & 63, w = t >> 6;
  const int so = t & 63, sg = t >> 6;
  const int cp = t & 31, g = t >> 5;
  const float* wsrc = &W1[(size_t)(j0 + so) * C + sg * 16];
  const float* xsrc = &outd[((size_t)b * C + 2 * cp) * N + p0 + g * 8];
  float4 wreg[4], xreg[4];
  auto ld = [&](int kc) {
    const float4* wp_ = (const float4*)(wsrc + kc);
    wreg[0] = wp_[0]; wreg[1] = wp_[1]; wreg[2] = wp_[2]; wreg[3] = wp_[3];
    const float4* x0_ = (const float4*)(xsrc + (size_t)kc * N);
    xreg[0] = x0_[0]; xreg[1] = x0_[1];
    const float4* x1_ = (const float4*)(xsrc + (size_t)(kc + 1) * N);
    xreg[2] = x1_[0]; xreg[3] = x1_[1];
  };
  f32x4 acc[4] = {};
  ld(0);
  for (int kc = 0; kc < C; kc += 64) {
    __syncthreads();
#pragma unroll
    for (int u = 0; u < 4; ++u) {
      const int c0 = sg * 16 + 4 * u;
      *(unsigned*)&Wl[swz(so, c0)]     = pack2(wreg[u].x, wreg[u].y);
      *(unsigned*)&Wl[swz(so, c0 + 2)] = pack2(wreg[u].z, wreg[u].w);
    }
    {
      float a0[8], a1[8];
      *(float4*)&a0[0] = xreg[0]; *(float4*)&a0[4] = xreg[1];
      *(float4*)&a1[0] = xreg[2]; *(float4*)&a1[4] = xreg[3];
#pragma unroll
      for (int i = 0; i < 8; ++i)
        *(unsigned*)&Xt[swz(g * 8 + i, 2 * cp)] = pack2(a0[i], a1[i]);
    }
    __syncthreads();
    if (kc + 64 < C) ld(kc + 64);
    const int mrow = w * 16 + (l & 15);
#pragma unroll
    for (int kk = 0; kk < 2; ++kk) {
      bf16x8 a = ldfrag(Xt, mrow, kk, l);
#pragma unroll
      for (int nt = 0; nt < 4; ++nt) {
        bf16x8 bf = ldfrag(Wl, nt * 16 + (l & 15), kk, l);
        acc[nt] = __builtin_amdgcn_mfma_f32_16x16x32_bf16(a, bf, acc[nt], 0, 0, 0);
      }
    }
  }
  const int pbase = w * 16 + 4 * (l >> 4);
#pragma unroll
  for (int nt = 0; nt < 4; ++nt) {
    const int jo = j0 + nt * 16 + (l & 15);
    const float bias = b1[jo];
#pragma unroll
    for (int r = 0; r < 4; ++r)
      h1b[(size_t)b * CQ * N + (size_t)jo * N + p0 + pbase + r] =
          __float2bfloat16(fmaxf(acc[nt][r] + bias, 0.f));
  }
}

// ---------------------------------------------------------------------------
// K5: att[b,p] = sigmoid(b_att2 + sum_j W_att2[j] * h1[b,j,p])
// ---------------------------------------------------------------------------
__global__ __launch_bounds__(256) void k_att2(const float* __restrict__ W2,
                                              const float* __restrict__ b2,
                                              const bf16* __restrict__ h1b,
                                              float* __restrict__ attb,
                                              float* __restrict__ out1) {
  const int idx = blockIdx.x * 256 + threadIdx.x;   // 0..8191
  const int b = idx >> 10, p = idx & 1023;
  float acc = b2[0];
  const bf16* hb = h1b + (size_t)b * CQ * N + p;
  for (int j = 0; j < CQ; ++j)
    acc += W2[j] * __bfloat162float(hb[(size_t)j * N]);
  const float sg = 1.f / (1.f + __expf(-acc));
  attb[idx] = sg;
  out1[idx] = sg;
}

// ---------------------------------------------------------------------------
// K6: out0 *= att  (in-place gate of fp32 d_out)
// ---------------------------------------------------------------------------
__global__ __launch_bounds__(256) void k_mul(float* __restrict__ out0,
                                             const float* __restrict__ attb) {
  const int idx = blockIdx.x * 256 + threadIdx.x;   // 0..4194303
  const int b = idx >> 19;
  const int p = idx & 1023;
  out0[idx] = out0[idx] * attb[b * 1024 + p];
}

// ---------------------------------------------------------------------------
extern "C" void kernel_launch(void* const* d_in, const int* in_sizes, int n_in,
                              void* d_out, int out_size, void* d_ws, size_t ws_size,
                              hipStream_t stream) {
  const float* x     = (const float*)d_in[0];
  const float* Wqkv  = (const float*)d_in[1];
  const float* Wproj = (const float*)d_in[2];
  const float* bproj = (const float*)d_in[3];
  const float* Watt1 = (const float*)d_in[4];
  const float* batt1 = (const float*)d_in[5];
  const float* Watt2 = (const float*)d_in[6];
  const float* batt2 = (const float*)d_in[7];

  char* ws = (char*)d_ws;
  bf16*  qkvb = (bf16*)(ws + QKV_OFF);
  bf16*  h1b  = (bf16*)(ws + H1_OFF);
  float* attb = (float*)(ws + ATT_OFF);

  float* out0 = (float*)d_out;
  float* out1 = out0 + (size_t)B * C * N;   // 4194304 floats

  k_qkv <<<dim3(16, 24, 8), 256, 0, stream>>>(Wqkv, x, qkvb);
  k_attn<<<dim3(16, 64),    256, 0, stream>>>(qkvb);
  k_proj<<<dim3(16, 8, 8),  256, 0, stream>>>(Wproj, bproj, qkvb, out0);
  k_att1<<<dim3(16, 2, 8),  256, 0, stream>>>(Watt1, batt1, out0, h1b);
  k_att2<<<32,    256, 0, stream>>>(Watt2, batt2, h1b, attb, out1);
  k_mul <<<16384, 256, 0, stream>>>(out0, attb);
}

// Round 8
// 241.761 us; speedup vs baseline: 6.6273x; 1.2067x over previous
//
#include <hip/hip_runtime.h>
#include <hip/hip_bf16.h>

using bf16 = __hip_bfloat16;
typedef __bf16 bf16x8 __attribute__((ext_vector_type(8)));
typedef float  f32x4  __attribute__((ext_vector_type(4)));

// Interface model (settled r0-r5): inputs fp32, output fp32.
// r6: MFMA qkv+attn -> 382. r7: MFMA proj+att1 -> 292; qkv prefetch NEUTRAL
// (tile too small: 8 MFMA vs 10 b128/iter), attn had 5M LDS bank conflicts
// (fp32 P stride-68 round-trip, 8-way) + 136MB FETCH (same-bh q-tile blocks
// spread across XCDs -> K/V L2 thrash).
// r8: k_qkv 128x128 tile (32 MFMA : 16 b128 per wave-iter); k_attn P->bf16
// swizzled tile (conflict-free b128 A-frags) + grid-dim swap (bh -> XCD
// affinity: linear id = bh + 64*qt, XCD = bh%8, 2MB K/V per XCD in 4MB L2);
// k_att2+k_mul fused into k_gate (1 block/CU, float4 gating).
// MFMA 16x16x32 layouts (r6/r7 verified):
//   A-frag: lane holds A[m=lane&15][k=(lane>>4)*8+j] (row-major [m][k] tile)
//   B-frag: lane holds B[k][n=lane&15] (tile stored [n][k])
//   C/D:    row=(lane>>4)*4+reg, col=lane&15
// LDS tiles: XOR-swizzled 16B atoms (atom' = atom ^ (row&7)) -> 0 conflicts.

static constexpr int B  = 8;
static constexpr int C  = 512;
static constexpr int N  = 1024;   // H*W
static constexpr int NH = 8;
static constexpr int DH = 64;
static constexpr int CQ = 128;    // C/4

// ws layout (bytes), 27.3 MB:
static constexpr size_t QKV_OFF  = 0;          // qkv bf16 [3][B,NH,N,DH] (o overwrites q)
static constexpr size_t H1_OFF   = 25165824;   // h1 bf16 [B,CQ,N]

__device__ __forceinline__ unsigned short f2bfu(float f) {
  union { float f; unsigned u; } v; v.f = f;
  unsigned u = v.u;
  return (unsigned short)((u + 0x7fffu + ((u >> 16) & 1u)) >> 16);  // RNE
}
__device__ __forceinline__ unsigned pack2(float lo, float hi) {
  return (unsigned)f2bfu(lo) | ((unsigned)f2bfu(hi) << 16);
}
__device__ __forceinline__ int swz(int row, int col) {
  return row * 64 + ((((col >> 3) ^ row) & 7) << 3) + (col & 7);
}
__device__ __forceinline__ bf16x8 ldfrag(const short* tl, int row, int kk, int lane) {
  const int atom = 4 * kk + (lane >> 4);
  return *(const bf16x8*)&tl[row * 64 + (((atom ^ row) & 7) << 3)];
}

// ---------------------------------------------------------------------------
// K1 (MFMA 128x128): qkv[b,o,p] = sum_c W[o,c] x[b,c,p] -> q/k/v [B,NH,N,DH]
// D[m=p][n=o]; per block 128p x 128o, 4 waves 2x2, per wave 64x64 (acc 4x4).
// Prefetch packs fp32->bf16 at load (32 VGPRs of prefetch state).
// ---------------------------------------------------------------------------
__global__ __launch_bounds__(256, 3) void k_qkv(const float* __restrict__ W,
                                                const float* __restrict__ x,
                                                bf16* __restrict__ qkv) {
  __shared__ __align__(16) short Al[128 * 64];  // x^T [p][c]
  __shared__ __align__(16) short Bl[128 * 64];  // W   [o][c]
  const int pt = blockIdx.x, ot = blockIdx.y, b = blockIdx.z;
  const int p0 = pt * 128, o0 = ot * 128;
  const int t = threadIdx.x, l = t & 63, w = t >> 6;
  const int wm = w & 1, wn = w >> 1;
  const int cp = t & 31, g0 = t >> 5;    // x staging: c-pair, p-chunks g0,g0+8
  const int so = t & 127, sc0 = t >> 7;  // W staging: o-row, chunks sc0,sc0+2
  const float* xsrc = &x[((size_t)b * C + 2 * cp) * N + p0];
  const float* wsrc = &W[(size_t)(o0 + so) * C];
  unsigned upx[16], upw[16];
  auto ld = [&](int kc) {
    const float* xa = xsrc + (size_t)kc * N;
#pragma unroll
    for (int s = 0; s < 2; ++s) {
      const int gp = (g0 + 8 * s) * 8;
      float4 r0 = *(const float4*)(xa + gp);
      float4 r1 = *(const float4*)(xa + gp + 4);
      float4 r2 = *(const float4*)(xa + N + gp);
      float4 r3 = *(const float4*)(xa + N + gp + 4);
      upx[8*s+0] = pack2(r0.x, r2.x); upx[8*s+1] = pack2(r0.y, r2.y);
      upx[8*s+2] = pack2(r0.z, r2.z); upx[8*s+3] = pack2(r0.w, r2.w);
      upx[8*s+4] = pack2(r1.x, r3.x); upx[8*s+5] = pack2(r1.y, r3.y);
      upx[8*s+6] = pack2(r1.z, r3.z); upx[8*s+7] = pack2(r1.w, r3.w);
    }
    const float* wa = wsrc + kc;
#pragma unroll
    for (int s = 0; s < 2; ++s) {
      const int cc = (sc0 + 2 * s) * 16;
#pragma unroll
      for (int u = 0; u < 4; ++u) {
        float4 f = *(const float4*)(wa + cc + 4 * u);
        upw[8*s+2*u]   = pack2(f.x, f.y);
        upw[8*s+2*u+1] = pack2(f.z, f.w);
      }
    }
  };
  f32x4 acc[4][4] = {};
  ld(0);
  for (int kc = 0; kc < C; kc += 64) {
    __syncthreads();
#pragma unroll
    for (int s = 0; s < 2; ++s)
#pragma unroll
      for (int i = 0; i < 8; ++i)
        *(unsigned*)&Al[swz((g0 + 8*s) * 8 + i, 2 * cp)] = upx[8*s+i];
#pragma unroll
    for (int s = 0; s < 2; ++s) {
      const int cc = (sc0 + 2 * s) * 16;
#pragma unroll
      for (int u = 0; u < 4; ++u) {
        *(unsigned*)&Bl[swz(so, cc + 4*u)]     = upw[8*s+2*u];
        *(unsigned*)&Bl[swz(so, cc + 4*u + 2)] = upw[8*s+2*u+1];
      }
    }
    __syncthreads();
    if (kc + 64 < C) ld(kc + 64);   // prefetch (packed) overlaps MFMA phase
#pragma unroll
    for (int kk = 0; kk < 2; ++kk) {
      bf16x8 af[4], bf[4];
#pragma unroll
      for (int i = 0; i < 4; ++i) af[i] = ldfrag(Al, wm*64 + i*16 + (l&15), kk, l);
#pragma unroll
      for (int j = 0; j < 4; ++j) bf[j] = ldfrag(Bl, wn*64 + j*16 + (l&15), kk, l);
#pragma unroll
      for (int i = 0; i < 4; ++i)
#pragma unroll
        for (int j = 0; j < 4; ++j)
          acc[i][j] = __builtin_amdgcn_mfma_f32_16x16x32_bf16(af[i], bf[j], acc[i][j], 0, 0, 0);
    }
  }
  const int on = o0 + wn * 64;           // wave's 64 o-cols = one head's d 0..63
  const int s = on >> 9, h = (on >> 6) & 7;
  bf16* dst = qkv + (size_t)s * (B * NH * N * DH) + (size_t)(b * NH + h) * N * DH;
  const int pb = p0 + wm * 64 + 4 * (l >> 4);
#pragma unroll
  for (int i = 0; i < 4; ++i)
#pragma unroll
    for (int j = 0; j < 4; ++j) {
      const int d = j * 16 + (l & 15);
#pragma unroll
      for (int r = 0; r < 4; ++r)
        dst[(size_t)(pb + i * 16 + r) * DH + d] = __float2bfloat16(acc[i][j][r]);
    }
}

// ---------------------------------------------------------------------------
// K2 (MFMA flash attention): grid (bh, qt) -> XCD affinity by bh%8.
// P stored bf16 in per-wave swizzled 16x64 tile (conflict-free b128 A-frags).
// O overwrites this block's own q rows.
// ---------------------------------------------------------------------------
__global__ __launch_bounds__(256) void k_attn(bf16* __restrict__ qkv) {
  __shared__ __align__(16) short Ql[64 * 64];
  __shared__ __align__(16) short Kl[64 * 64];
  __shared__ __align__(16) short Vt[64 * 64];   // V^T: [dim][key]
  __shared__ __align__(16) short Pb[4 * 16 * 64];
  const int bh = blockIdx.x, qt = blockIdx.y;   // bh-major -> XCD = bh%8
  const int t = threadIdx.x, l = t & 63, w = t >> 6;
  const bf16* kp = qkv + (size_t)B * NH * N * DH;
  const bf16* vp = kp + (size_t)B * NH * N * DH;
  const uint4* gkb = (const uint4*)(kp + (size_t)bh * N * DH);
  const uint4* gvb = (const uint4*)(vp + (size_t)bh * N * DH);
  const int kpr = t & 31, g = t >> 5;

  {  // stage Q
    const uint4* gq = (const uint4*)(qkv + ((size_t)bh * N + qt * 64) * DH);
    for (int c = t; c < 512; c += 256) {
      int row = c >> 3, atom = c & 7;
      *(uint4*)&Ql[row * 64 + (((atom ^ row) & 7) << 3)] = gq[c];
    }
  }
  __syncthreads();
  const int mrow = w * 16 + (l & 15);
  bf16x8 qf[2] = { ldfrag(Ql, mrow, 0, l), ldfrag(Ql, mrow, 1, l) };
  float m_run[4] = {-1e30f, -1e30f, -1e30f, -1e30f};
  float l_run[4] = {};
  f32x4 oacc[4] = {};
  short* Pw = &Pb[w * 1024];

  union u4s { uint4 v; unsigned short s[8]; };
  uint4 kreg0, kreg1; u4s v0, v1;
  auto ld = [&](int mt) {
    const uint4* gk = gkb + mt * 512;
    kreg0 = gk[t]; kreg1 = gk[t + 256];
    const uint4* gv = gvb + mt * 512;
    v0.v = gv[16 * kpr + g]; v1.v = gv[16 * kpr + 8 + g];
  };
  ld(0);

  for (int mt = 0; mt < 16; ++mt) {
    __syncthreads();
    {  // write prefetched K (direct) + V^T (pack key-pairs)
      const int r0 = t >> 3, a0 = t & 7;
      *(uint4*)&Kl[r0 * 64 + (((a0 ^ r0) & 7) << 3)] = kreg0;
      const int r1 = r0 + 32;
      *(uint4*)&Kl[r1 * 64 + (((a0 ^ r1) & 7) << 3)] = kreg1;
#pragma unroll
      for (int j = 0; j < 8; ++j)
        *(unsigned*)&Vt[swz(g * 8 + j, 2 * kpr)] =
            (unsigned)v0.s[j] | ((unsigned)v1.s[j] << 16);
    }
    __syncthreads();
    if (mt < 15) ld(mt + 1);   // prefetch overlaps compute
    // S = Q K^T / 8
    f32x4 sacc[4] = {};
#pragma unroll
    for (int kk = 0; kk < 2; ++kk)
#pragma unroll
      for (int nt = 0; nt < 4; ++nt) {
        bf16x8 bf = ldfrag(Kl, nt * 16 + (l & 15), kk, l);
        sacc[nt] = __builtin_amdgcn_mfma_f32_16x16x32_bf16(qf[kk], bf, sacc[nt], 0, 0, 0);
      }
#pragma unroll
    for (int nt = 0; nt < 4; ++nt) sacc[nt] *= 0.125f;
    // online softmax; P -> bf16 swizzled tile
    float alpha[4];
#pragma unroll
    for (int r = 0; r < 4; ++r) {
      float mloc = fmaxf(fmaxf(sacc[0][r], sacc[1][r]),
                         fmaxf(sacc[2][r], sacc[3][r]));
#pragma unroll
      for (int off = 1; off < 16; off <<= 1)
        mloc = fmaxf(mloc, __shfl_xor(mloc, off));
      const float mn = fmaxf(m_run[r], mloc);
      alpha[r] = __expf(m_run[r] - mn);
      m_run[r] = mn;
      float lloc = 0.f;
      const int prow = 4 * (l >> 4) + r;
#pragma unroll
      for (int nt = 0; nt < 4; ++nt) {
        float pv = __expf(sacc[nt][r] - mn);
        Pw[swz(prow, (l & 15) + 16 * nt)] = (short)f2bfu(pv);
        lloc += pv;
      }
#pragma unroll
      for (int off = 1; off < 16; off <<= 1)
        lloc += __shfl_xor(lloc, off);
      l_run[r] = l_run[r] * alpha[r] + lloc;
    }
#pragma unroll
    for (int nt = 0; nt < 4; ++nt)
#pragma unroll
      for (int r = 0; r < 4; ++r)
        oacc[nt][r] *= alpha[r];
    // O += P V  (A-frag = conflict-free b128 from Pb; B from Vt)
#pragma unroll
    for (int kk = 0; kk < 2; ++kk) {
      bf16x8 pa = ldfrag(Pw, l & 15, kk, l);
#pragma unroll
      for (int nt = 0; nt < 4; ++nt) {
        bf16x8 bf = ldfrag(Vt, nt * 16 + (l & 15), kk, l);
        oacc[nt] = __builtin_amdgcn_mfma_f32_16x16x32_bf16(pa, bf, oacc[nt], 0, 0, 0);
      }
    }
  }
  const int qrow = qt * 64 + w * 16 + 4 * (l >> 4);
#pragma unroll
  for (int r = 0; r < 4; ++r) {
    const float inv = 1.f / l_run[r];
#pragma unroll
    for (int nt = 0; nt < 4; ++nt)
      qkv[((size_t)bh * N + qrow + r) * DH + nt * 16 + (l & 15)] =
          __float2bfloat16(oacc[nt][r] * inv);
  }
}

// ---------------------------------------------------------------------------
// K3 (MFMA + prefetch): out[b,co,p] = bias + sum_ci Wp[co,ci]*o_rs[b,ci,p]
// o_rs[ci][pp] = obase[(2ci+eps)*64 + pp]  (h,eps block-constant). fp32 out.
// ---------------------------------------------------------------------------
__global__ __launch_bounds__(256) void k_proj(const float* __restrict__ Wp,
                                              const float* __restrict__ bp,
                                              const bf16* __restrict__ obuf,
                                              float* __restrict__ outd) {
  __shared__ __align__(16) short Wl[64 * 64];
  __shared__ __align__(16) short Ot[64 * 64];
  const int pt = blockIdx.x, ct = blockIdx.y, b = blockIdx.z;
  const int p0 = pt * 64, co0 = ct * 64;
  const int h = (p0 & 511) >> 6, eps = p0 >> 9;
  const int t = threadIdx.x, l = t & 63, w = t >> 6;
  const int so = t & 63, sg = t >> 6;
  const int cp = t & 31, g = t >> 5;
  const float* wsrc = &Wp[(size_t)(co0 + so) * C + sg * 16];
  const bf16* obase = obuf + (size_t)(b * NH + h) * N * DH;
  union u4s { uint4 v; unsigned short s[8]; };
  float4 wreg[4]; u4s o0r, o1r;
  auto ld = [&](int kc) {
    const float4* wp_ = (const float4*)(wsrc + kc);
    wreg[0] = wp_[0]; wreg[1] = wp_[1]; wreg[2] = wp_[2]; wreg[3] = wp_[3];
    const int ci0 = kc + 2 * cp;
    o0r.v = *(const uint4*)(obase + (size_t)(2 * ci0 + eps) * 64 + g * 8);
    o1r.v = *(const uint4*)(obase + (size_t)(2 * ci0 + 2 + eps) * 64 + g * 8);
  };
  f32x4 acc[4] = {};
  ld(0);
  for (int kc = 0; kc < C; kc += 64) {
    __syncthreads();
#pragma unroll
    for (int u = 0; u < 4; ++u) {
      const int c0 = sg * 16 + 4 * u;
      *(unsigned*)&Wl[swz(so, c0)]     = pack2(wreg[u].x, wreg[u].y);
      *(unsigned*)&Wl[swz(so, c0 + 2)] = pack2(wreg[u].z, wreg[u].w);
    }
#pragma unroll
    for (int i = 0; i < 8; ++i)
      *(unsigned*)&Ot[swz(g * 8 + i, 2 * cp)] =
          (unsigned)o0r.s[i] | ((unsigned)o1r.s[i] << 16);
    __syncthreads();
    if (kc + 64 < C) ld(kc + 64);
    const int mrow = w * 16 + (l & 15);
#pragma unroll
    for (int kk = 0; kk < 2; ++kk) {
      bf16x8 a = ldfrag(Ot, mrow, kk, l);
#pragma unroll
      for (int nt = 0; nt < 4; ++nt) {
        bf16x8 bf = ldfrag(Wl, nt * 16 + (l & 15), kk, l);
        acc[nt] = __builtin_amdgcn_mfma_f32_16x16x32_bf16(a, bf, acc[nt], 0, 0, 0);
      }
    }
  }
  const int pbase = w * 16 + 4 * (l >> 4);
#pragma unroll
  for (int nt = 0; nt < 4; ++nt) {
    const int co = co0 + nt * 16 + (l & 15);
    const float bias = bp[co];
#pragma unroll
    for (int r = 0; r < 4; ++r)
      outd[(size_t)b * C * N + (size_t)co * N + p0 + pbase + r] = acc[nt][r] + bias;
  }
}

// ---------------------------------------------------------------------------
// K4 (MFMA + prefetch): h1[b,j,p] = relu(b1[j] + sum_ci W1[j,ci]*out[b,ci,p])
// ---------------------------------------------------------------------------
__global__ __launch_bounds__(256) void k_att1(const float* __restrict__ W1,
                                              const float* __restrict__ b1,
                                              const float* __restrict__ outd,
                                              bf16* __restrict__ h1b) {
  __shared__ __align__(16) short Wl[64 * 64];
  __shared__ __align__(16) short Xt[64 * 64];
  const int pt = blockIdx.x, jt = blockIdx.y, b = blockIdx.z;
  const int p0 = pt * 64, j0 = jt * 64;
  const int t = threadIdx.x, l = t & 63, w = t >> 6;
  const int so = t & 63, sg = t >> 6;
  const int cp = t & 31, g = t >> 5;
  const float* wsrc = &W1[(size_t)(j0 + so) * C + sg * 16];
  const float* xsrc = &outd[((size_t)b * C + 2 * cp) * N + p0 + g * 8];
  float4 wreg[4], xreg[4];
  auto ld = [&](int kc) {
    const float4* wp_ = (const float4*)(wsrc + kc);
    wreg[0] = wp_[0]; wreg[1] = wp_[1]; wreg[2] = wp_[2]; wreg[3] = wp_[3];
    const float4* x0_ = (const float4*)(xsrc + (size_t)kc * N);
    xreg[0] = x0_[0]; xreg[1] = x0_[1];
    const float4* x1_ = (const float4*)(xsrc + (size_t)(kc + 1) * N);
    xreg[2] = x1_[0]; xreg[3] = x1_[1];
  };
  f32x4 acc[4] = {};
  ld(0);
  for (int kc = 0; kc < C; kc += 64) {
    __syncthreads();
#pragma unroll
    for (int u = 0; u < 4; ++u) {
      const int c0 = sg * 16 + 4 * u;
      *(unsigned*)&Wl[swz(so, c0)]     = pack2(wreg[u].x, wreg[u].y);
      *(unsigned*)&Wl[swz(so, c0 + 2)] = pack2(wreg[u].z, wreg[u].w);
    }
    {
      float a0[8], a1[8];
      *(float4*)&a0[0] = xreg[0]; *(float4*)&a0[4] = xreg[1];
      *(float4*)&a1[0] = xreg[2]; *(float4*)&a1[4] = xreg[3];
#pragma unroll
      for (int i = 0; i < 8; ++i)
        *(unsigned*)&Xt[swz(g * 8 + i, 2 * cp)] = pack2(a0[i], a1[i]);
    }
    __syncthreads();
    if (kc + 64 < C) ld(kc + 64);
    const int mrow = w * 16 + (l & 15);
#pragma unroll
    for (int kk = 0; kk < 2; ++kk) {
      bf16x8 a = ldfrag(Xt, mrow, kk, l);
#pragma unroll
      for (int nt = 0; nt < 4; ++nt) {
        bf16x8 bf = ldfrag(Wl, nt * 16 + (l & 15), kk, l);
        acc[nt] = __builtin_amdgcn_mfma_f32_16x16x32_bf16(a, bf, acc[nt], 0, 0, 0);
      }
    }
  }
  const int pbase = w * 16 + 4 * (l >> 4);
#pragma unroll
  for (int nt = 0; nt < 4; ++nt) {
    const int jo = j0 + nt * 16 + (l & 15);
    const float bias = b1[jo];
#pragma unroll
    for (int r = 0; r < 4; ++r)
      h1b[(size_t)b * CQ * N + (size_t)jo * N + p0 + pbase + r] =
          __float2bfloat16(fmaxf(acc[nt][r] + bias, 0.f));
  }
}

// ---------------------------------------------------------------------------
// K5 (fused att2+sigmoid+gate): one block per (b, 32 p's); 256 blocks = 1/CU.
// att = sigmoid(b2 + W2 . h1[:,p]); out1 = att; out0[b,:,p] *= att (float4).
// ---------------------------------------------------------------------------
__global__ __launch_bounds__(256) void k_gate(const float* __restrict__ W2,
                                              const float* __restrict__ b2,
                                              const bf16* __restrict__ h1b,
                                              float* __restrict__ out0,
                                              float* __restrict__ out1) {
  __shared__ float red[8][32];
  __shared__ __align__(16) float att[32];
  const int blk = blockIdx.x, t = threadIdx.x;
  const int b = blk >> 5, p0 = (blk & 31) * 32;
  const int pl = t & 31, jg = t >> 5;
  float acc = 0.f;
  const bf16* hb = h1b + ((size_t)b * CQ + jg * 16) * N + p0 + pl;
#pragma unroll
  for (int jj = 0; jj < 16; ++jj)
    acc += W2[jg * 16 + jj] * __bfloat162float(hb[(size_t)jj * N]);
  red[jg][pl] = acc;
  __syncthreads();
  if (t < 32) {
    float a = b2[0];
#pragma unroll
    for (int k = 0; k < 8; ++k) a += red[k][t];
    const float sg = 1.f / (1.f + __expf(-a));
    att[t] = sg;
    out1[b * N + p0 + t] = sg;
  }
  __syncthreads();
  const int p4 = t & 7, cc = t >> 3;           // 8 float4-lanes x 32 c-lanes
  float4* ob4 = (float4*)(out0 + (size_t)b * C * N + p0);
  const float4 sg4 = *(const float4*)&att[4 * p4];
  for (int c = cc; c < C; c += 32) {
    float4 v = ob4[c * 256 + p4];
    v.x *= sg4.x; v.y *= sg4.y; v.z *= sg4.z; v.w *= sg4.w;
    ob4[c * 256 + p4] = v;
  }
}

// ---------------------------------------------------------------------------
extern "C" void kernel_launch(void* const* d_in, const int* in_sizes, int n_in,
                              void* d_out, int out_size, void* d_ws, size_t ws_size,
                              hipStream_t stream) {
  const float* x     = (const float*)d_in[0];
  const float* Wqkv  = (const float*)d_in[1];
  const float* Wproj = (const float*)d_in[2];
  const float* bproj = (const float*)d_in[3];
  const float* Watt1 = (const float*)d_in[4];
  const float* batt1 = (const float*)d_in[5];
  const float* Watt2 = (const float*)d_in[6];
  const float* batt2 = (const float*)d_in[7];

  char* ws = (char*)d_ws;
  bf16* qkvb = (bf16*)(ws + QKV_OFF);
  bf16* h1b  = (bf16*)(ws + H1_OFF);

  float* out0 = (float*)d_out;
  float* out1 = out0 + (size_t)B * C * N;   // 4194304 floats

  k_qkv <<<dim3(8, 12, 8), 256, 0, stream>>>(Wqkv, x, qkvb);
  k_attn<<<dim3(64, 16),   256, 0, stream>>>(qkvb);
  k_proj<<<dim3(16, 8, 8), 256, 0, stream>>>(Wproj, bproj, qkvb, out0);
  k_att1<<<dim3(16, 2, 8), 256, 0, stream>>>(Watt1, batt1, out0, h1b);
  k_gate<<<256, 256, 0, stream>>>(Watt2, batt2, h1b, out0, out1);
}

// Round 9
// 213.577 us; speedup vs baseline: 7.5019x; 1.1320x over previous
//
#include <hip/hip_runtime.h>
#include <hip/hip_bf16.h>

using bf16 = __hip_bfloat16;
typedef __bf16 bf16x8 __attribute__((ext_vector_type(8)));
typedef float  f32x4  __attribute__((ext_vector_type(4)));

// Interface model (settled r0-r5): inputs fp32, output fp32.
// r6: MFMA qkv+attn -> 382. r7: MFMA proj+att1 -> 292. r8: 128^2 qkv tile,
// attn P->bf16 (conflicts 5M->0) + bh-major grid (FETCH 136->12MB) -> 242,
// attn now softmax-VALU-bound (VALUBusy 40%, MfmaUtil 9%).
// r9: TRANSPOSED attention pipeline: S^T = K.Q^T (A=Kl, B=Ql, same tiles),
// lane's 16 S-values share one q-row -> row reduce = 15 reg-ops + 2 shfls
// (was 32 shfls/iter), single m/l/alpha per lane (was 4). PV as O^T = V^T.P^T
// (B = P tile [qrow][key], natural C-layout writes, paired dword stores).
// pack2 -> v_cvt_pk_bf16_f32 everywhere.
// MFMA 16x16x32 layouts (r6-r8 verified):
//   A-frag: lane holds A[m=lane&15][k=(lane>>4)*8+j] (row-major [m][k] tile)
//   B-frag: lane holds B[k][n=lane&15] (tile stored [n][k])
//   C/D:    row=4*(lane>>4)+reg, col=lane&15
// LDS tiles: XOR-swizzled 16B atoms (atom' = atom ^ (row&7)) -> 0 conflicts.

static constexpr int B  = 8;
static constexpr int C  = 512;
static constexpr int N  = 1024;   // H*W
static constexpr int NH = 8;
static constexpr int DH = 64;
static constexpr int CQ = 128;    // C/4

// ws layout (bytes), 27.3 MB:
static constexpr size_t QKV_OFF  = 0;          // qkv bf16 [3][B,NH,N,DH] (o overwrites q)
static constexpr size_t H1_OFF   = 25165824;   // h1 bf16 [B,CQ,N]

__device__ __forceinline__ unsigned pack2(float lo, float hi) {
  __hip_bfloat162 h = __float22bfloat162_rn(make_float2(lo, hi));
  return *(unsigned*)&h;   // x = low 16 bits
}
__device__ __forceinline__ int swz(int row, int col) {
  return row * 64 + ((((col >> 3) ^ row) & 7) << 3) + (col & 7);
}
__device__ __forceinline__ bf16x8 ldfrag(const short* tl, int row, int kk, int lane) {
  const int atom = 4 * kk + (lane >> 4);
  return *(const bf16x8*)&tl[row * 64 + (((atom ^ row) & 7) << 3)];
}

// ---------------------------------------------------------------------------
// K1 (MFMA 128x128): qkv[b,o,p] = sum_c W[o,c] x[b,c,p] -> q/k/v [B,NH,N,DH]
// ---------------------------------------------------------------------------
__global__ __launch_bounds__(256, 3) void k_qkv(const float* __restrict__ W,
                                                const float* __restrict__ x,
                                                bf16* __restrict__ qkv) {
  __shared__ __align__(16) short Al[128 * 64];  // x^T [p][c]
  __shared__ __align__(16) short Bl[128 * 64];  // W   [o][c]
  const int pt = blockIdx.x, ot = blockIdx.y, b = blockIdx.z;
  const int p0 = pt * 128, o0 = ot * 128;
  const int t = threadIdx.x, l = t & 63, w = t >> 6;
  const int wm = w & 1, wn = w >> 1;
  const int cp = t & 31, g0 = t >> 5;
  const int so = t & 127, sc0 = t >> 7;
  const float* xsrc = &x[((size_t)b * C + 2 * cp) * N + p0];
  const float* wsrc = &W[(size_t)(o0 + so) * C];
  unsigned upx[16], upw[16];
  auto ld = [&](int kc) {
    const float* xa = xsrc + (size_t)kc * N;
#pragma unroll
    for (int s = 0; s < 2; ++s) {
      const int gp = (g0 + 8 * s) * 8;
      float4 r0 = *(const float4*)(xa + gp);
      float4 r1 = *(const float4*)(xa + gp + 4);
      float4 r2 = *(const float4*)(xa + N + gp);
      float4 r3 = *(const float4*)(xa + N + gp + 4);
      upx[8*s+0] = pack2(r0.x, r2.x); upx[8*s+1] = pack2(r0.y, r2.y);
      upx[8*s+2] = pack2(r0.z, r2.z); upx[8*s+3] = pack2(r0.w, r2.w);
      upx[8*s+4] = pack2(r1.x, r3.x); upx[8*s+5] = pack2(r1.y, r3.y);
      upx[8*s+6] = pack2(r1.z, r3.z); upx[8*s+7] = pack2(r1.w, r3.w);
    }
    const float* wa = wsrc + kc;
#pragma unroll
    for (int s = 0; s < 2; ++s) {
      const int cc = (sc0 + 2 * s) * 16;
#pragma unroll
      for (int u = 0; u < 4; ++u) {
        float4 f = *(const float4*)(wa + cc + 4 * u);
        upw[8*s+2*u]   = pack2(f.x, f.y);
        upw[8*s+2*u+1] = pack2(f.z, f.w);
      }
    }
  };
  f32x4 acc[4][4] = {};
  ld(0);
  for (int kc = 0; kc < C; kc += 64) {
    __syncthreads();
#pragma unroll
    for (int s = 0; s < 2; ++s)
#pragma unroll
      for (int i = 0; i < 8; ++i)
        *(unsigned*)&Al[swz((g0 + 8*s) * 8 + i, 2 * cp)] = upx[8*s+i];
#pragma unroll
    for (int s = 0; s < 2; ++s) {
      const int cc = (sc0 + 2 * s) * 16;
#pragma unroll
      for (int u = 0; u < 4; ++u) {
        *(unsigned*)&Bl[swz(so, cc + 4*u)]     = upw[8*s+2*u];
        *(unsigned*)&Bl[swz(so, cc + 4*u + 2)] = upw[8*s+2*u+1];
      }
    }
    __syncthreads();
    if (kc + 64 < C) ld(kc + 64);
#pragma unroll
    for (int kk = 0; kk < 2; ++kk) {
      bf16x8 af[4], bf[4];
#pragma unroll
      for (int i = 0; i < 4; ++i) af[i] = ldfrag(Al, wm*64 + i*16 + (l&15), kk, l);
#pragma unroll
      for (int j = 0; j < 4; ++j) bf[j] = ldfrag(Bl, wn*64 + j*16 + (l&15), kk, l);
#pragma unroll
      for (int i = 0; i < 4; ++i)
#pragma unroll
        for (int j = 0; j < 4; ++j)
          acc[i][j] = __builtin_amdgcn_mfma_f32_16x16x32_bf16(af[i], bf[j], acc[i][j], 0, 0, 0);
    }
  }
  const int on = o0 + wn * 64;
  const int s = on >> 9, h = (on >> 6) & 7;
  bf16* dst = qkv + (size_t)s * (B * NH * N * DH) + (size_t)(b * NH + h) * N * DH;
  const int pb = p0 + wm * 64 + 4 * (l >> 4);
#pragma unroll
  for (int i = 0; i < 4; ++i)
#pragma unroll
    for (int j = 0; j < 4; ++j) {
      const int d = j * 16 + (l & 15);
#pragma unroll
      for (int r = 0; r < 4; ++r)
        dst[(size_t)(pb + i * 16 + r) * DH + d] = __float2bfloat16(acc[i][j][r]);
    }
}

// ---------------------------------------------------------------------------
// K2 (MFMA flash attention, transposed): grid (bh, qt) -> XCD = bh%8.
// S^T = K.Q^T; softmax state per lane (one q-row); O^T = V^T.P^T; epilogue
// transposes O^T through the P tile for coalesced stores.
// ---------------------------------------------------------------------------
__global__ __launch_bounds__(256) void k_attn(bf16* __restrict__ qkv) {
  __shared__ __align__(16) short Ql[64 * 64];
  __shared__ __align__(16) short Kl[64 * 64];
  __shared__ __align__(16) short Vt[64 * 64];   // V^T: [dim][key]
  __shared__ __align__(16) short Pb[4 * 16 * 64];
  const int bh = blockIdx.x, qt = blockIdx.y;
  const int t = threadIdx.x, l = t & 63, w = t >> 6;
  const bf16* kp = qkv + (size_t)B * NH * N * DH;
  const bf16* vp = kp + (size_t)B * NH * N * DH;
  const uint4* gkb = (const uint4*)(kp + (size_t)bh * N * DH);
  const uint4* gvb = (const uint4*)(vp + (size_t)bh * N * DH);
  const int kpr = t & 31, g = t >> 5;

  {  // stage Q: [qrow][dim], swizzled
    const uint4* gq = (const uint4*)(qkv + ((size_t)bh * N + qt * 64) * DH);
    for (int c = t; c < 512; c += 256) {
      int row = c >> 3, atom = c & 7;
      *(uint4*)&Ql[row * 64 + (((atom ^ row) & 7) << 3)] = gq[c];
    }
  }
  __syncthreads();
  // B-operand for QK (q-rows of this wave) -- same addressing as A-frags
  bf16x8 qf[2] = { ldfrag(Ql, w * 16 + (l & 15), 0, l),
                   ldfrag(Ql, w * 16 + (l & 15), 1, l) };
  float m_run = -1e30f, l_run = 0.f;
  f32x4 oacc[4] = {};   // O^T: [dim-tile][qrow]
  short* Pw = &Pb[w * 1024];

  union u4s { uint4 v; unsigned short s[8]; };
  uint4 kreg0, kreg1; u4s v0, v1;
  auto ld = [&](int mt) {
    const uint4* gk = gkb + mt * 512;
    kreg0 = gk[t]; kreg1 = gk[t + 256];
    const uint4* gv = gvb + mt * 512;
    v0.v = gv[16 * kpr + g]; v1.v = gv[16 * kpr + 8 + g];
  };
  ld(0);

  for (int mt = 0; mt < 16; ++mt) {
    __syncthreads();
    {  // write prefetched K (direct) + V^T (pack key-pairs)
      const int r0 = t >> 3, a0 = t & 7;
      *(uint4*)&Kl[r0 * 64 + (((a0 ^ r0) & 7) << 3)] = kreg0;
      const int r1 = r0 + 32;
      *(uint4*)&Kl[r1 * 64 + (((a0 ^ r1) & 7) << 3)] = kreg1;
#pragma unroll
      for (int j = 0; j < 8; ++j)
        *(unsigned*)&Vt[swz(g * 8 + j, 2 * kpr)] =
            (unsigned)v0.s[j] | ((unsigned)v1.s[j] << 16);
    }
    __syncthreads();
    if (mt < 15) ld(mt + 1);
    // S^T = K.Q^T / 8 :  sacc[kt][r] = S[key = kt*16+4*(l>>4)+r][qrow]
    f32x4 sacc[4] = {};
#pragma unroll
    for (int kk = 0; kk < 2; ++kk)
#pragma unroll
      for (int kt = 0; kt < 4; ++kt) {
        bf16x8 af = ldfrag(Kl, kt * 16 + (l & 15), kk, l);
        sacc[kt] = __builtin_amdgcn_mfma_f32_16x16x32_bf16(af, qf[kk], sacc[kt], 0, 0, 0);
      }
#pragma unroll
    for (int kt = 0; kt < 4; ++kt) sacc[kt] *= 0.125f;
    // online softmax: lane's 16 values share one q-row
    float smax = sacc[0][0];
#pragma unroll
    for (int kt = 0; kt < 4; ++kt)
#pragma unroll
      for (int r = 0; r < 4; ++r) smax = fmaxf(smax, sacc[kt][r]);
    smax = fmaxf(smax, __shfl_xor(smax, 16));
    smax = fmaxf(smax, __shfl_xor(smax, 32));
    const float mn = fmaxf(m_run, smax);
    const float alpha = __expf(m_run - mn);
    m_run = mn;
    float psum = 0.f;
    const int qr = l & 15, cb0 = 4 * (l >> 4);
#pragma unroll
    for (int kt = 0; kt < 4; ++kt) {
      float p0v = __expf(sacc[kt][0] - mn);
      float p1v = __expf(sacc[kt][1] - mn);
      float p2v = __expf(sacc[kt][2] - mn);
      float p3v = __expf(sacc[kt][3] - mn);
      psum += (p0v + p1v) + (p2v + p3v);
      const int cb = kt * 16 + cb0;
      *(unsigned*)&Pw[swz(qr, cb)]     = pack2(p0v, p1v);
      *(unsigned*)&Pw[swz(qr, cb + 2)] = pack2(p2v, p3v);
    }
    psum += __shfl_xor(psum, 16);
    psum += __shfl_xor(psum, 32);
    l_run = l_run * alpha + psum;
#pragma unroll
    for (int dt = 0; dt < 4; ++dt) oacc[dt] *= alpha;
    // O^T += V^T . P^T  (A = Vt rows, B = P tile [qrow][key])
#pragma unroll
    for (int kk = 0; kk < 2; ++kk) {
      bf16x8 pbf = ldfrag(Pw, l & 15, kk, l);
#pragma unroll
      for (int dt = 0; dt < 4; ++dt) {
        bf16x8 av = ldfrag(Vt, dt * 16 + (l & 15), kk, l);
        oacc[dt] = __builtin_amdgcn_mfma_f32_16x16x32_bf16(av, pbf, oacc[dt], 0, 0, 0);
      }
    }
  }
  // epilogue: O = (O^T)^T via P tile, then coalesced uint4 stores
  __syncthreads();   // safety: all PV reads drained before Pw reuse
  const float inv = 1.f / l_run;
  const int qr = l & 15, cb0 = 4 * (l >> 4);
#pragma unroll
  for (int dt = 0; dt < 4; ++dt) {
    const int cb = dt * 16 + cb0;
    *(unsigned*)&Pw[swz(qr, cb)]     = pack2(oacc[dt][0] * inv, oacc[dt][1] * inv);
    *(unsigned*)&Pw[swz(qr, cb + 2)] = pack2(oacc[dt][2] * inv, oacc[dt][3] * inv);
  }
  __syncthreads();
  bf16* obase = qkv + ((size_t)bh * N + qt * 64 + w * 16) * DH;
#pragma unroll
  for (int i = 0; i < 2; ++i) {
    const int e = l + 64 * i, row = e >> 3, atom = e & 7;
    uint4 val = *(const uint4*)&Pw[row * 64 + (((atom ^ row) & 7) << 3)];
    *(uint4*)(obase + (size_t)row * DH + atom * 8) = val;
  }
}

// ---------------------------------------------------------------------------
// K3 (MFMA + prefetch): out[b,co,p] = bias + sum_ci Wp[co,ci]*o_rs[b,ci,p]
// o_rs[ci][pp] = obase[(2ci+eps)*64 + pp]  (h,eps block-constant). fp32 out.
// ---------------------------------------------------------------------------
__global__ __launch_bounds__(256) void k_proj(const float* __restrict__ Wp,
                                              const float* __restrict__ bp,
                                              const bf16* __restrict__ obuf,
                                              float* __restrict__ outd) {
  __shared__ __align__(16) short Wl[64 * 64];
  __shared__ __align__(16) short Ot[64 * 64];
  const int pt = blockIdx.x, ct = blockIdx.y, b = blockIdx.z;
  const int p0 = pt * 64, co0 = ct * 64;
  const int h = (p0 & 511) >> 6, eps = p0 >> 9;
  const int t = threadIdx.x, l = t & 63, w = t >> 6;
  const int so = t & 63, sg = t >> 6;
  const int cp = t & 31, g = t >> 5;
  const float* wsrc = &Wp[(size_t)(co0 + so) * C + sg * 16];
  const bf16* obase = obuf + (size_t)(b * NH + h) * N * DH;
  union u4s { uint4 v; unsigned short s[8]; };
  float4 wreg[4]; u4s o0r, o1r;
  auto ld = [&](int kc) {
    const float4* wp_ = (const float4*)(wsrc + kc);
    wreg[0] = wp_[0]; wreg[1] = wp_[1]; wreg[2] = wp_[2]; wreg[3] = wp_[3];
    const int ci0 = kc + 2 * cp;
    o0r.v = *(const uint4*)(obase + (size_t)(2 * ci0 + eps) * 64 + g * 8);
    o1r.v = *(const uint4*)(obase + (size_t)(2 * ci0 + 2 + eps) * 64 + g * 8);
  };
  f32x4 acc[4] = {};
  ld(0);
  for (int kc = 0; kc < C; kc += 64) {
    __syncthreads();
#pragma unroll
    for (int u = 0; u < 4; ++u) {
      const int c0 = sg * 16 + 4 * u;
      *(unsigned*)&Wl[swz(so, c0)]     = pack2(wreg[u].x, wreg[u].y);
      *(unsigned*)&Wl[swz(so, c0 + 2)] = pack2(wreg[u].z, wreg[u].w);
    }
#pragma unroll
    for (int i = 0; i < 8; ++i)
      *(unsigned*)&Ot[swz(g * 8 + i, 2 * cp)] =
          (unsigned)o0r.s[i] | ((unsigned)o1r.s[i] << 16);
    __syncthreads();
    if (kc + 64 < C) ld(kc + 64);
    const int mrow = w * 16 + (l & 15);
#pragma unroll
    for (int kk = 0; kk < 2; ++kk) {
      bf16x8 a = ldfrag(Ot, mrow, kk, l);
#pragma unroll
      for (int nt = 0; nt < 4; ++nt) {
        bf16x8 bf = ldfrag(Wl, nt * 16 + (l & 15), kk, l);
        acc[nt] = __builtin_amdgcn_mfma_f32_16x16x32_bf16(a, bf, acc[nt], 0, 0, 0);
      }
    }
  }
  const int pbase = w * 16 + 4 * (l >> 4);
#pragma unroll
  for (int nt = 0; nt < 4; ++nt) {
    const int co = co0 + nt * 16 + (l & 15);
    const float bias = bp[co];
#pragma unroll
    for (int r = 0; r < 4; ++r)
      outd[(size_t)b * C * N + (size_t)co * N + p0 + pbase + r] = acc[nt][r] + bias;
  }
}

// ---------------------------------------------------------------------------
// K4 (MFMA + prefetch): h1[b,j,p] = relu(b1[j] + sum_ci W1[j,ci]*out[b,ci,p])
// ---------------------------------------------------------------------------
__global__ __launch_bounds__(256) void k_att1(const float* __restrict__ W1,
                                              const float* __restrict__ b1,
                                              const float* __restrict__ outd,
                                              bf16* __restrict__ h1b) {
  __shared__ __align__(16) short Wl[64 * 64];
  __shared__ __align__(16) short Xt[64 * 64];
  const int pt = blockIdx.x, jt = blockIdx.y, b = blockIdx.z;
  const int p0 = pt * 64, j0 = jt * 64;
  const int t = threadIdx.x, l = t & 63, w = t >> 6;
  const int so = t & 63, sg = t >> 6;
  const int cp = t & 31, g = t >> 5;
  const float* wsrc = &W1[(size_t)(j0 + so) * C + sg * 16];
  const float* xsrc = &outd[((size_t)b * C + 2 * cp) * N + p0 + g * 8];
  float4 wreg[4], xreg[4];
  auto ld = [&](int kc) {
    const float4* wp_ = (const float4*)(wsrc + kc);
    wreg[0] = wp_[0]; wreg[1] = wp_[1]; wreg[2] = wp_[2]; wreg[3] = wp_[3];
    const float4* x0_ = (const float4*)(xsrc + (size_t)kc * N);
    xreg[0] = x0_[0]; xreg[1] = x0_[1];
    const float4* x1_ = (const float4*)(xsrc + (size_t)(kc + 1) * N);
    xreg[2] = x1_[0]; xreg[3] = x1_[1];
  };
  f32x4 acc[4] = {};
  ld(0);
  for (int kc = 0; kc < C; kc += 64) {
    __syncthreads();
#pragma unroll
    for (int u = 0; u < 4; ++u) {
      const int c0 = sg * 16 + 4 * u;
      *(unsigned*)&Wl[swz(so, c0)]     = pack2(wreg[u].x, wreg[u].y);
      *(unsigned*)&Wl[swz(so, c0 + 2)] = pack2(wreg[u].z, wreg[u].w);
    }
    {
      float a0[8], a1[8];
      *(float4*)&a0[0] = xreg[0]; *(float4*)&a0[4] = xreg[1];
      *(float4*)&a1[0] = xreg[2]; *(float4*)&a1[4] = xreg[3];
#pragma unroll
      for (int i = 0; i < 8; ++i)
        *(unsigned*)&Xt[swz(g * 8 + i, 2 * cp)] = pack2(a0[i], a1[i]);
    }
    __syncthreads();
    if (kc + 64 < C) ld(kc + 64);
    const int mrow = w * 16 + (l & 15);
#pragma unroll
    for (int kk = 0; kk < 2; ++kk) {
      bf16x8 a = ldfrag(Xt, mrow, kk, l);
#pragma unroll
      for (int nt = 0; nt < 4; ++nt) {
        bf16x8 bf = ldfrag(Wl, nt * 16 + (l & 15), kk, l);
        acc[nt] = __builtin_amdgcn_mfma_f32_16x16x32_bf16(a, bf, acc[nt], 0, 0, 0);
      }
    }
  }
  const int pbase = w * 16 + 4 * (l >> 4);
#pragma unroll
  for (int nt = 0; nt < 4; ++nt) {
    const int jo = j0 + nt * 16 + (l & 15);
    const float bias = b1[jo];
#pragma unroll
    for (int r = 0; r < 4; ++r)
      h1b[(size_t)b * CQ * N + (size_t)jo * N + p0 + pbase + r] =
          __float2bfloat16(fmaxf(acc[nt][r] + bias, 0.f));
  }
}

// ---------------------------------------------------------------------------
// K5 (fused att2+sigmoid+gate): one block per (b, 32 p's); 256 blocks.
// ---------------------------------------------------------------------------
__global__ __launch_bounds__(256) void k_gate(const float* __restrict__ W2,
                                              const float* __restrict__ b2,
                                              const bf16* __restrict__ h1b,
                                              float* __restrict__ out0,
                                              float* __restrict__ out1) {
  __shared__ float red[8][32];
  __shared__ __align__(16) float att[32];
  const int blk = blockIdx.x, t = threadIdx.x;
  const int b = blk >> 5, p0 = (blk & 31) * 32;
  const int pl = t & 31, jg = t >> 5;
  float acc = 0.f;
  const bf16* hb = h1b + ((size_t)b * CQ + jg * 16) * N + p0 + pl;
#pragma unroll
  for (int jj = 0; jj < 16; ++jj)
    acc += W2[jg * 16 + jj] * __bfloat162float(hb[(size_t)jj * N]);
  red[jg][pl] = acc;
  __syncthreads();
  if (t < 32) {
    float a = b2[0];
#pragma unroll
    for (int k = 0; k < 8; ++k) a += red[k][t];
    const float sg = 1.f / (1.f + __expf(-a));
    att[t] = sg;
    out1[b * N + p0 + t] = sg;
  }
  __syncthreads();
  const int p4 = t & 7, cc = t >> 3;
  float4* ob4 = (float4*)(out0 + (size_t)b * C * N + p0);
  const float4 sg4 = *(const float4*)&att[4 * p4];
  for (int c = cc; c < C; c += 32) {
    float4 v = ob4[c * 256 + p4];
    v.x *= sg4.x; v.y *= sg4.y; v.z *= sg4.z; v.w *= sg4.w;
    ob4[c * 256 + p4] = v;
  }
}

// ---------------------------------------------------------------------------
extern "C" void kernel_launch(void* const* d_in, const int* in_sizes, int n_in,
                              void* d_out, int out_size, void* d_ws, size_t ws_size,
                              hipStream_t stream) {
  const float* x     = (const float*)d_in[0];
  const float* Wqkv  = (const float*)d_in[1];
  const float* Wproj = (const float*)d_in[2];
  const float* bproj = (const float*)d_in[3];
  const float* Watt1 = (const float*)d_in[4];
  const float* batt1 = (const float*)d_in[5];
  const float* Watt2 = (const float*)d_in[6];
  const float* batt2 = (const float*)d_in[7];

  char* ws = (char*)d_ws;
  bf16* qkvb = (bf16*)(ws + QKV_OFF);
  bf16* h1b  = (bf16*)(ws + H1_OFF);

  float* out0 = (float*)d_out;
  float* out1 = out0 + (size_t)B * C * N;   // 4194304 floats

  k_qkv <<<dim3(8, 12, 8), 256, 0, stream>>>(Wqkv, x, qkvb);
  k_attn<<<dim3(64, 16),   256, 0, stream>>>(qkvb);
  k_proj<<<dim3(16, 8, 8), 256, 0, stream>>>(Wproj, bproj, qkvb, out0);
  k_att1<<<dim3(16, 2, 8), 256, 0, stream>>>(Watt1, batt1, out0, h1b);
  k_gate<<<256, 256, 0, stream>>>(Watt2, batt2, h1b, out0, out1);
}

// Round 10
// 212.825 us; speedup vs baseline: 7.5284x; 1.0035x over previous
//
#include <hip/hip_runtime.h>
#include <hip/hip_bf16.h>

using bf16 = __hip_bfloat16;
typedef __bf16 bf16x8 __attribute__((ext_vector_type(8)));
typedef float  f32x4  __attribute__((ext_vector_type(4)));

// Interface model (settled r0-r5): inputs fp32, output fp32.
// r6 MFMA qkv+attn -> 382. r7 MFMA proj+att1 -> 292. r8 128^2 qkv + attn
// L2-affinity/P-bf16 -> 242. r9 transposed-softmax attn -> 213.6.
// r10: coalesced LDS-transpose epilogues for qkv/proj/att1 (proj's old store:
// 64 segments per wave-store at 4KB stride; att1 2-B lanes at 2KB stride;
// qkv 4-seg). k_qkv swaps MFMA operands (D[m=o][n=p]) so acc r-pairs pack to
// d-contiguous dwords; Al/Bl reused as output tiles (uint4 coalesced stores).
// MFMA 16x16x32 layouts (r6-r9 verified):
//   A-frag: lane holds A[m=lane&15][k=(lane>>4)*8+j] (row-major [m][k] tile)
//   B-frag: lane holds B[k][n=lane&15] (tile stored [n][k])
//   C/D:    row=4*(lane>>4)+reg, col=lane&15
// LDS tiles: XOR-swizzled 16B atoms (atom' = atom ^ (row&7)).

static constexpr int B  = 8;
static constexpr int C  = 512;
static constexpr int N  = 1024;   // H*W
static constexpr int NH = 8;
static constexpr int DH = 64;
static constexpr int CQ = 128;    // C/4

// ws layout (bytes), 27.3 MB:
static constexpr size_t QKV_OFF  = 0;          // qkv bf16 [3][B,NH,N,DH] (o overwrites q)
static constexpr size_t H1_OFF   = 25165824;   // h1 bf16 [B,CQ,N]

__device__ __forceinline__ unsigned pack2(float lo, float hi) {
  __hip_bfloat162 h = __float22bfloat162_rn(make_float2(lo, hi));
  return *(unsigned*)&h;
}
__device__ __forceinline__ int swz(int row, int col) {
  return row * 64 + ((((col >> 3) ^ row) & 7) << 3) + (col & 7);
}
__device__ __forceinline__ bf16x8 ldfrag(const short* tl, int row, int kk, int lane) {
  const int atom = 4 * kk + (lane >> 4);
  return *(const bf16x8*)&tl[row * 64 + (((atom ^ row) & 7) << 3)];
}
// fp32 64x64 tile, swizzled 16B atoms (4 floats): index in floats
__device__ __forceinline__ int fswz(int row, int col) {
  return row * 64 + ((((col >> 2) ^ row) & 15) << 2) + (col & 3);
}

// ---------------------------------------------------------------------------
// K1 (MFMA 128x128): qkv[b,o,p] = sum_c W[o,c] x[b,c,p] -> q/k/v [B,NH,N,DH]
// D[m=o][n=p]: A = W tile [o][c] (Bl), B = x^T tile [p][c] (Al).
// Epilogue: acc -> Al/Bl as two [p 128][d 64] tiles -> coalesced uint4 stores.
// ---------------------------------------------------------------------------
__global__ __launch_bounds__(256, 3) void k_qkv(const float* __restrict__ W,
                                                const float* __restrict__ x,
                                                bf16* __restrict__ qkv) {
  __shared__ __align__(16) short Al[128 * 64];  // x^T [p][c]
  __shared__ __align__(16) short Bl[128 * 64];  // W   [o][c]
  const int pt = blockIdx.x, ot = blockIdx.y, b = blockIdx.z;
  const int p0 = pt * 128, o0 = ot * 128;
  const int t = threadIdx.x, l = t & 63, w = t >> 6;
  const int wo = w & 1, wp = w >> 1;
  const int cp = t & 31, g0 = t >> 5;
  const int so = t & 127, sc0 = t >> 7;
  const float* xsrc = &x[((size_t)b * C + 2 * cp) * N + p0];
  const float* wsrc = &W[(size_t)(o0 + so) * C];
  unsigned upx[16], upw[16];
  auto ld = [&](int kc) {
    const float* xa = xsrc + (size_t)kc * N;
#pragma unroll
    for (int s = 0; s < 2; ++s) {
      const int gp = (g0 + 8 * s) * 8;
      float4 r0 = *(const float4*)(xa + gp);
      float4 r1 = *(const float4*)(xa + gp + 4);
      float4 r2 = *(const float4*)(xa + N + gp);
      float4 r3 = *(const float4*)(xa + N + gp + 4);
      upx[8*s+0] = pack2(r0.x, r2.x); upx[8*s+1] = pack2(r0.y, r2.y);
      upx[8*s+2] = pack2(r0.z, r2.z); upx[8*s+3] = pack2(r0.w, r2.w);
      upx[8*s+4] = pack2(r1.x, r3.x); upx[8*s+5] = pack2(r1.y, r3.y);
      upx[8*s+6] = pack2(r1.z, r3.z); upx[8*s+7] = pack2(r1.w, r3.w);
    }
    const float* wa = wsrc + kc;
#pragma unroll
    for (int s = 0; s < 2; ++s) {
      const int cc = (sc0 + 2 * s) * 16;
#pragma unroll
      for (int u = 0; u < 4; ++u) {
        float4 f = *(const float4*)(wa + cc + 4 * u);
        upw[8*s+2*u]   = pack2(f.x, f.y);
        upw[8*s+2*u+1] = pack2(f.z, f.w);
      }
    }
  };
  f32x4 acc[4][4] = {};
  ld(0);
  for (int kc = 0; kc < C; kc += 64) {
    __syncthreads();
#pragma unroll
    for (int s = 0; s < 2; ++s)
#pragma unroll
      for (int i = 0; i < 8; ++i)
        *(unsigned*)&Al[swz((g0 + 8*s) * 8 + i, 2 * cp)] = upx[8*s+i];
#pragma unroll
    for (int s = 0; s < 2; ++s) {
      const int cc = (sc0 + 2 * s) * 16;
#pragma unroll
      for (int u = 0; u < 4; ++u) {
        *(unsigned*)&Bl[swz(so, cc + 4*u)]     = upw[8*s+2*u];
        *(unsigned*)&Bl[swz(so, cc + 4*u + 2)] = upw[8*s+2*u+1];
      }
    }
    __syncthreads();
    if (kc + 64 < C) ld(kc + 64);
#pragma unroll
    for (int kk = 0; kk < 2; ++kk) {
      bf16x8 af[4], bf[4];
#pragma unroll
      for (int i = 0; i < 4; ++i) af[i] = ldfrag(Bl, wo*64 + i*16 + (l&15), kk, l);
#pragma unroll
      for (int j = 0; j < 4; ++j) bf[j] = ldfrag(Al, wp*64 + j*16 + (l&15), kk, l);
#pragma unroll
      for (int i = 0; i < 4; ++i)
#pragma unroll
        for (int j = 0; j < 4; ++j)
          acc[i][j] = __builtin_amdgcn_mfma_f32_16x16x32_bf16(af[i], bf[j], acc[i][j], 0, 0, 0);
    }
  }
  // epilogue: acc -> tiles [p][d] (tile wo: Al for o-chunk0, Bl chunk1)
  __syncthreads();
  {
    short* T = wo ? Bl : Al;
#pragma unroll
    for (int i = 0; i < 4; ++i) {
      const int d = i * 16 + 4 * (l >> 4);
#pragma unroll
      for (int j = 0; j < 4; ++j) {
        const int p = wp * 64 + j * 16 + (l & 15);
        *(unsigned*)&T[swz(p, d)]     = pack2(acc[i][j][0], acc[i][j][1]);
        *(unsigned*)&T[swz(p, d + 2)] = pack2(acc[i][j][2], acc[i][j][3]);
      }
    }
  }
  __syncthreads();
  {
    const int oc0 = o0, oc1 = o0 + 64;
    bf16* dst0 = qkv + (size_t)(oc0 >> 9) * (B * NH * N * DH) +
                 (size_t)(b * NH + ((oc0 >> 6) & 7)) * N * DH + (size_t)p0 * DH;
    bf16* dst1 = qkv + (size_t)(oc1 >> 9) * (B * NH * N * DH) +
                 (size_t)(b * NH + ((oc1 >> 6) & 7)) * N * DH + (size_t)p0 * DH;
#pragma unroll
    for (int it = 0; it < 8; ++it) {
      const int e = t + 256 * it;
      const int tile = e >> 10, row = (e >> 3) & 127, atom = e & 7;
      const short* T = tile ? Bl : Al;
      uint4 val = *(const uint4*)&T[row * 64 + (((atom ^ row) & 7) << 3)];
      bf16* dst = tile ? dst1 : dst0;
      *(uint4*)(dst + (size_t)row * DH + atom * 8) = val;
    }
  }
}

// ---------------------------------------------------------------------------
// K2 (MFMA flash attention, transposed): unchanged from r9.
// ---------------------------------------------------------------------------
__global__ __launch_bounds__(256) void k_attn(bf16* __restrict__ qkv) {
  __shared__ __align__(16) short Ql[64 * 64];
  __shared__ __align__(16) short Kl[64 * 64];
  __shared__ __align__(16) short Vt[64 * 64];
  __shared__ __align__(16) short Pb[4 * 16 * 64];
  const int bh = blockIdx.x, qt = blockIdx.y;
  const int t = threadIdx.x, l = t & 63, w = t >> 6;
  const bf16* kp = qkv + (size_t)B * NH * N * DH;
  const bf16* vp = kp + (size_t)B * NH * N * DH;
  const uint4* gkb = (const uint4*)(kp + (size_t)bh * N * DH);
  const uint4* gvb = (const uint4*)(vp + (size_t)bh * N * DH);
  const int kpr = t & 31, g = t >> 5;

  {
    const uint4* gq = (const uint4*)(qkv + ((size_t)bh * N + qt * 64) * DH);
    for (int c = t; c < 512; c += 256) {
      int row = c >> 3, atom = c & 7;
      *(uint4*)&Ql[row * 64 + (((atom ^ row) & 7) << 3)] = gq[c];
    }
  }
  __syncthreads();
  bf16x8 qf[2] = { ldfrag(Ql, w * 16 + (l & 15), 0, l),
                   ldfrag(Ql, w * 16 + (l & 15), 1, l) };
  float m_run = -1e30f, l_run = 0.f;
  f32x4 oacc[4] = {};
  short* Pw = &Pb[w * 1024];

  union u4s { uint4 v; unsigned short s[8]; };
  uint4 kreg0, kreg1; u4s v0, v1;
  auto ld = [&](int mt) {
    const uint4* gk = gkb + mt * 512;
    kreg0 = gk[t]; kreg1 = gk[t + 256];
    const uint4* gv = gvb + mt * 512;
    v0.v = gv[16 * kpr + g]; v1.v = gv[16 * kpr + 8 + g];
  };
  ld(0);

  for (int mt = 0; mt < 16; ++mt) {
    __syncthreads();
    {
      const int r0 = t >> 3, a0 = t & 7;
      *(uint4*)&Kl[r0 * 64 + (((a0 ^ r0) & 7) << 3)] = kreg0;
      const int r1 = r0 + 32;
      *(uint4*)&Kl[r1 * 64 + (((a0 ^ r1) & 7) << 3)] = kreg1;
#pragma unroll
      for (int j = 0; j < 8; ++j)
        *(unsigned*)&Vt[swz(g * 8 + j, 2 * kpr)] =
            (unsigned)v0.s[j] | ((unsigned)v1.s[j] << 16);
    }
    __syncthreads();
    if (mt < 15) ld(mt + 1);
    f32x4 sacc[4] = {};
#pragma unroll
    for (int kk = 0; kk < 2; ++kk)
#pragma unroll
      for (int kt = 0; kt < 4; ++kt) {
        bf16x8 af = ldfrag(Kl, kt * 16 + (l & 15), kk, l);
        sacc[kt] = __builtin_amdgcn_mfma_f32_16x16x32_bf16(af, qf[kk], sacc[kt], 0, 0, 0);
      }
#pragma unroll
    for (int kt = 0; kt < 4; ++kt) sacc[kt] *= 0.125f;
    float smax = sacc[0][0];
#pragma unroll
    for (int kt = 0; kt < 4; ++kt)
#pragma unroll
      for (int r = 0; r < 4; ++r) smax = fmaxf(smax, sacc[kt][r]);
    smax = fmaxf(smax, __shfl_xor(smax, 16));
    smax = fmaxf(smax, __shfl_xor(smax, 32));
    const float mn = fmaxf(m_run, smax);
    const float alpha = __expf(m_run - mn);
    m_run = mn;
    float psum = 0.f;
    const int qr = l & 15, cb0 = 4 * (l >> 4);
#pragma unroll
    for (int kt = 0; kt < 4; ++kt) {
      float p0v = __expf(sacc[kt][0] - mn);
      float p1v = __expf(sacc[kt][1] - mn);
      float p2v = __expf(sacc[kt][2] - mn);
      float p3v = __expf(sacc[kt][3] - mn);
      psum += (p0v + p1v) + (p2v + p3v);
      const int cb = kt * 16 + cb0;
      *(unsigned*)&Pw[swz(qr, cb)]     = pack2(p0v, p1v);
      *(unsigned*)&Pw[swz(qr, cb + 2)] = pack2(p2v, p3v);
    }
    psum += __shfl_xor(psum, 16);
    psum += __shfl_xor(psum, 32);
    l_run = l_run * alpha + psum;
#pragma unroll
    for (int dt = 0; dt < 4; ++dt) oacc[dt] *= alpha;
#pragma unroll
    for (int kk = 0; kk < 2; ++kk) {
      bf16x8 pbf = ldfrag(Pw, l & 15, kk, l);
#pragma unroll
      for (int dt = 0; dt < 4; ++dt) {
        bf16x8 av = ldfrag(Vt, dt * 16 + (l & 15), kk, l);
        oacc[dt] = __builtin_amdgcn_mfma_f32_16x16x32_bf16(av, pbf, oacc[dt], 0, 0, 0);
      }
    }
  }
  __syncthreads();
  const float inv = 1.f / l_run;
  const int qr = l & 15, cb0 = 4 * (l >> 4);
#pragma unroll
  for (int dt = 0; dt < 4; ++dt) {
    const int cb = dt * 16 + cb0;
    *(unsigned*)&Pw[swz(qr, cb)]     = pack2(oacc[dt][0] * inv, oacc[dt][1] * inv);
    *(unsigned*)&Pw[swz(qr, cb + 2)] = pack2(oacc[dt][2] * inv, oacc[dt][3] * inv);
  }
  __syncthreads();
  bf16* obase = qkv + ((size_t)bh * N + qt * 64 + w * 16) * DH;
#pragma unroll
  for (int i = 0; i < 2; ++i) {
    const int e = l + 64 * i, row = e >> 3, atom = e & 7;
    uint4 val = *(const uint4*)&Pw[row * 64 + (((atom ^ row) & 7) << 3)];
    *(uint4*)(obase + (size_t)row * DH + atom * 8) = val;
  }
}

// ---------------------------------------------------------------------------
// K3 (MFMA): out[b,co,p] = bias + sum_ci Wp[co,ci]*o_rs[b,ci,p], fp32 out.
// Epilogue via swizzled 64x64 fp32 LDS tile -> coalesced float4 stores.
// ---------------------------------------------------------------------------
__global__ __launch_bounds__(256) void k_proj(const float* __restrict__ Wp,
                                              const float* __restrict__ bp,
                                              const bf16* __restrict__ obuf,
                                              float* __restrict__ outd) {
  __shared__ __align__(16) short SM[8192];   // Wl | Ot ; epilogue: fp32 64x64
  short* Wl = SM;
  short* Ot = SM + 4096;
  const int pt = blockIdx.x, ct = blockIdx.y, b = blockIdx.z;
  const int p0 = pt * 64, co0 = ct * 64;
  const int h = (p0 & 511) >> 6, eps = p0 >> 9;
  const int t = threadIdx.x, l = t & 63, w = t >> 6;
  const int so = t & 63, sg = t >> 6;
  const int cp = t & 31, g = t >> 5;
  const float* wsrc = &Wp[(size_t)(co0 + so) * C + sg * 16];
  const bf16* obase = obuf + (size_t)(b * NH + h) * N * DH;
  union u4s { uint4 v; unsigned short s[8]; };
  float4 wreg[4]; u4s o0r, o1r;
  auto ld = [&](int kc) {
    const float4* wp_ = (const float4*)(wsrc + kc);
    wreg[0] = wp_[0]; wreg[1] = wp_[1]; wreg[2] = wp_[2]; wreg[3] = wp_[3];
    const int ci0 = kc + 2 * cp;
    o0r.v = *(const uint4*)(obase + (size_t)(2 * ci0 + eps) * 64 + g * 8);
    o1r.v = *(const uint4*)(obase + (size_t)(2 * ci0 + 2 + eps) * 64 + g * 8);
  };
  f32x4 acc[4] = {};
  ld(0);
  for (int kc = 0; kc < C; kc += 64) {
    __syncthreads();
#pragma unroll
    for (int u = 0; u < 4; ++u) {
      const int c0 = sg * 16 + 4 * u;
      *(unsigned*)&Wl[swz(so, c0)]     = pack2(wreg[u].x, wreg[u].y);
      *(unsigned*)&Wl[swz(so, c0 + 2)] = pack2(wreg[u].z, wreg[u].w);
    }
#pragma unroll
    for (int i = 0; i < 8; ++i)
      *(unsigned*)&Ot[swz(g * 8 + i, 2 * cp)] =
          (unsigned)o0r.s[i] | ((unsigned)o1r.s[i] << 16);
    __syncthreads();
    if (kc + 64 < C) ld(kc + 64);
    const int mrow = w * 16 + (l & 15);
#pragma unroll
    for (int kk = 0; kk < 2; ++kk) {
      bf16x8 a = ldfrag(Ot, mrow, kk, l);
#pragma unroll
      for (int nt = 0; nt < 4; ++nt) {
        bf16x8 bf = ldfrag(Wl, nt * 16 + (l & 15), kk, l);
        acc[nt] = __builtin_amdgcn_mfma_f32_16x16x32_bf16(a, bf, acc[nt], 0, 0, 0);
      }
    }
  }
  // epilogue: biased acc -> fp32 tile [co][pp], then coalesced float4 stores
  __syncthreads();
  {
    float* Ep = (float*)SM;
    const int pp = w * 16 + 4 * (l >> 4);
#pragma unroll
    for (int nt = 0; nt < 4; ++nt) {
      const int co = nt * 16 + (l & 15);
      const float bias = bp[co0 + co];
      *(float2*)&Ep[fswz(co, pp)]     = make_float2(acc[nt][0] + bias, acc[nt][1] + bias);
      *(float2*)&Ep[fswz(co, pp + 2)] = make_float2(acc[nt][2] + bias, acc[nt][3] + bias);
    }
  }
  __syncthreads();
  {
    const float* Ep = (const float*)SM;
#pragma unroll
    for (int it = 0; it < 4; ++it) {
      const int e = t + 256 * it;
      const int co = e >> 4, a = e & 15;
      float4 v = *(const float4*)&Ep[co * 64 + (((a ^ (co & 15)) & 15) << 2)];
      *(float4*)&outd[(size_t)b * C * N + (size_t)(co0 + co) * N + p0 + a * 4] = v;
    }
  }
}

// ---------------------------------------------------------------------------
// K4 (MFMA): h1[b,j,p] = relu(b1[j] + sum_ci W1[j,ci]*out[b,ci,p]); bf16 h1.
// Epilogue via swizzled 64x64 bf16 LDS tile -> coalesced uint4 stores.
// ---------------------------------------------------------------------------
__global__ __launch_bounds__(256) void k_att1(const float* __restrict__ W1,
                                              const float* __restrict__ b1,
                                              const float* __restrict__ outd,
                                              bf16* __restrict__ h1b) {
  __shared__ __align__(16) short Wl[64 * 64];
  __shared__ __align__(16) short Xt[64 * 64];
  const int pt = blockIdx.x, jt = blockIdx.y, b = blockIdx.z;
  const int p0 = pt * 64, j0 = jt * 64;
  const int t = threadIdx.x, l = t & 63, w = t >> 6;
  const int so = t & 63, sg = t >> 6;
  const int cp = t & 31, g = t >> 5;
  const float* wsrc = &W1[(size_t)(j0 + so) * C + sg * 16];
  const float* xsrc = &outd[((size_t)b * C + 2 * cp) * N + p0 + g * 8];
  float4 wreg[4], xreg[4];
  auto ld = [&](int kc) {
    const float4* wp_ = (const float4*)(wsrc + kc);
    wreg[0] = wp_[0]; wreg[1] = wp_[1]; wreg[2] = wp_[2]; wreg[3] = wp_[3];
    const float4* x0_ = (const float4*)(xsrc + (size_t)kc * N);
    xreg[0] = x0_[0]; xreg[1] = x0_[1];
    const float4* x1_ = (const float4*)(xsrc + (size_t)(kc + 1) * N);
    xreg[2] = x1_[0]; xreg[3] = x1_[1];
  };
  f32x4 acc[4] = {};
  ld(0);
  for (int kc = 0; kc < C; kc += 64) {
    __syncthreads();
#pragma unroll
    for (int u = 0; u < 4; ++u) {
      const int c0 = sg * 16 + 4 * u;
      *(unsigned*)&Wl[swz(so, c0)]     = pack2(wreg[u].x, wreg[u].y);
      *(unsigned*)&Wl[swz(so, c0 + 2)] = pack2(wreg[u].z, wreg[u].w);
    }
    {
      float a0[8], a1[8];
      *(float4*)&a0[0] = xreg[0]; *(float4*)&a0[4] = xreg[1];
      *(float4*)&a1[0] = xreg[2]; *(float4*)&a1[4] = xreg[3];
#pragma unroll
      for (int i = 0; i < 8; ++i)
        *(unsigned*)&Xt[swz(g * 8 + i, 2 * cp)] = pack2(a0[i], a1[i]);
    }
    __syncthreads();
    if (kc + 64 < C) ld(kc + 64);
    const int mrow = w * 16 + (l & 15);
#pragma unroll
    for (int kk = 0; kk < 2; ++kk) {
      bf16x8 a = ldfrag(Xt, mrow, kk, l);
#pragma unroll
      for (int nt = 0; nt < 4; ++nt) {
        bf16x8 bf = ldfrag(Wl, nt * 16 + (l & 15), kk, l);
        acc[nt] = __builtin_amdgcn_mfma_f32_16x16x32_bf16(a, bf, acc[nt], 0, 0, 0);
      }
    }
  }
  // epilogue: relu(acc+bias) -> bf16 tile [jo][pp] in Wl -> uint4 stores
  __syncthreads();
  {
    const int pp = w * 16 + 4 * (l >> 4);
#pragma unroll
    for (int nt = 0; nt < 4; ++nt) {
      const int jo = nt * 16 + (l & 15);
      const float bias = b1[j0 + jo];
      float v0 = fmaxf(acc[nt][0] + bias, 0.f), v1 = fmaxf(acc[nt][1] + bias, 0.f);
      float v2 = fmaxf(acc[nt][2] + bias, 0.f), v3 = fmaxf(acc[nt][3] + bias, 0.f);
      *(unsigned*)&Wl[swz(jo, pp)]     = pack2(v0, v1);
      *(unsigned*)&Wl[swz(jo, pp + 2)] = pack2(v2, v3);
    }
  }
  __syncthreads();
#pragma unroll
  for (int it = 0; it < 2; ++it) {
    const int e = t + 256 * it;
    const int row = e >> 3, atom = e & 7;
    uint4 val = *(const uint4*)&Wl[row * 64 + (((atom ^ row) & 7) << 3)];
    *(uint4*)((bf16*)h1b + (size_t)b * CQ * N + (size_t)(j0 + row) * N + p0 + atom * 8) = val;
  }
}

// ---------------------------------------------------------------------------
// K5 (fused att2+sigmoid+gate): unchanged from r9.
// ---------------------------------------------------------------------------
__global__ __launch_bounds__(256) void k_gate(const float* __restrict__ W2,
                                              const float* __restrict__ b2,
                                              const bf16* __restrict__ h1b,
                                              float* __restrict__ out0,
                                              float* __restrict__ out1) {
  __shared__ float red[8][32];
  __shared__ __align__(16) float att[32];
  const int blk = blockIdx.x, t = threadIdx.x;
  const int b = blk >> 5, p0 = (blk & 31) * 32;
  const int pl = t & 31, jg = t >> 5;
  float acc = 0.f;
  const bf16* hb = h1b + ((size_t)b * CQ + jg * 16) * N + p0 + pl;
#pragma unroll
  for (int jj = 0; jj < 16; ++jj)
    acc += W2[jg * 16 + jj] * __bfloat162float(hb[(size_t)jj * N]);
  red[jg][pl] = acc;
  __syncthreads();
  if (t < 32) {
    float a = b2[0];
#pragma unroll
    for (int k = 0; k < 8; ++k) a += red[k][t];
    const float sg = 1.f / (1.f + __expf(-a));
    att[t] = sg;
    out1[b * N + p0 + t] = sg;
  }
  __syncthreads();
  const int p4 = t & 7, cc = t >> 3;
  float4* ob4 = (float4*)(out0 + (size_t)b * C * N + p0);
  const float4 sg4 = *(const float4*)&att[4 * p4];
  for (int c = cc; c < C; c += 32) {
    float4 v = ob4[c * 256 + p4];
    v.x *= sg4.x; v.y *= sg4.y; v.z *= sg4.z; v.w *= sg4.w;
    ob4[c * 256 + p4] = v;
  }
}

// ---------------------------------------------------------------------------
extern "C" void kernel_launch(void* const* d_in, const int* in_sizes, int n_in,
                              void* d_out, int out_size, void* d_ws, size_t ws_size,
                              hipStream_t stream) {
  const float* x     = (const float*)d_in[0];
  const float* Wqkv  = (const float*)d_in[1];
  const float* Wproj = (const float*)d_in[2];
  const float* bproj = (const float*)d_in[3];
  const float* Watt1 = (const float*)d_in[4];
  const float* batt1 = (const float*)d_in[5];
  const float* Watt2 = (const float*)d_in[6];
  const float* batt2 = (const float*)d_in[7];

  char* ws = (char*)d_ws;
  bf16* qkvb = (bf16*)(ws + QKV_OFF);
  bf16* h1b  = (bf16*)(ws + H1_OFF);

  float* out0 = (float*)d_out;
  float* out1 = out0 + (size_t)B * C * N;   // 4194304 floats

  k_qkv <<<dim3(8, 12, 8), 256, 0, stream>>>(Wqkv, x, qkvb);
  k_attn<<<dim3(64, 16),   256, 0, stream>>>(qkvb);
  k_proj<<<dim3(16, 8, 8), 256, 0, stream>>>(Wproj, bproj, qkvb, out0);
  k_att1<<<dim3(16, 2, 8), 256, 0, stream>>>(Watt1, batt1, out0, h1b);
  k_gate<<<256, 256, 0, stream>>>(Watt2, batt2, h1b, out0, out1);
}